// Round 5
// baseline (420.534 us; speedup 1.0000x reference)
//
#include <hip/hip_runtime.h>
#include <hip/hip_bf16.h>

typedef __attribute__((ext_vector_type(8))) short short8;
typedef __attribute__((ext_vector_type(4))) float f32x4;

__device__ __forceinline__ ushort f2b(float f) {
    union { float f; uint u; } v; v.f = f;
    uint u = v.u;
    u += 0x7fffu + ((u >> 16) & 1u);   // RNE
    return (ushort)(u >> 16);
}
__device__ __forceinline__ float blo(uint u) { return __uint_as_float(u << 16); }
__device__ __forceinline__ float bhi(uint u) { return __uint_as_float(u & 0xffff0000u); }

// ================= CSR build: bucket counting sort =================
// bucket = node >> 10  (NB = ceil(N/1024) <= 128)

__global__ __launch_bounds__(256) void k_bucket_hist(const int* __restrict__ col, int E,
                                                     int NB, int* __restrict__ bcnt) {
    __shared__ int h[128];
    int tid = threadIdx.x;
    if (tid < 128) h[tid] = 0;
    __syncthreads();
    for (int e = blockIdx.x * blockDim.x + tid; e < E; e += gridDim.x * blockDim.x)
        atomicAdd(&h[col[e] >> 10], 1);
    __syncthreads();
    if (tid < NB && h[tid]) atomicAdd(&bcnt[tid], h[tid]);
}

// single block, 128 threads
__global__ void k_scan_buckets(const int* __restrict__ bcnt, int NB,
                               int* __restrict__ boffs, int* __restrict__ bcursor) {
    __shared__ int tmp[128];
    int t = threadIdx.x;
    int orig = (t < NB) ? bcnt[t] : 0;
    tmp[t] = orig;
    __syncthreads();
    for (int off = 1; off < 128; off <<= 1) {
        int v = (t >= off) ? tmp[t - off] : 0;
        __syncthreads();
        tmp[t] += v;
        __syncthreads();
    }
    if (t < NB) {
        int ex = tmp[t] - orig;
        boffs[t] = ex;
        bcursor[t] = ex;
    }
    if (t == 0) boffs[NB] = tmp[127];
}

// scatter edges into bucket-contiguous ebuf; per-block chunk reservation
__global__ __launch_bounds__(256) void k_bucket_scatter(const int* __restrict__ ei, int E,
                                                        int NB, int* __restrict__ bcursor,
                                                        int2* __restrict__ ebuf) {
    __shared__ int h[128], gb[128], lc[128];
    int tid = threadIdx.x;
    if (tid < 128) { h[tid] = 0; lc[tid] = 0; }
    __syncthreads();
    int e0 = blockIdx.x * 2048;
    int r[8], c[8], bk[8];
#pragma unroll
    for (int u = 0; u < 8; ++u) {
        int e = e0 + u * 256 + tid;
        if (e < E) {
            r[u] = ei[e];
            c[u] = ei[E + e];
            bk[u] = c[u] >> 10;
            atomicAdd(&h[bk[u]], 1);
        }
    }
    __syncthreads();
    if (tid < NB && h[tid]) gb[tid] = atomicAdd(&bcursor[tid], h[tid]);
    __syncthreads();
#pragma unroll
    for (int u = 0; u < 8; ++u) {
        int e = e0 + u * 256 + tid;
        if (e < E) {
            int p = gb[bk[u]] + atomicAdd(&lc[bk[u]], 1);
            ebuf[p] = make_int2(r[u], c[u]);
        }
    }
}

// one block per bucket: LDS counting sort -> csr, offs, dinv
__global__ __launch_bounds__(256) void k_bucket_sort(const int2* __restrict__ ebuf,
                                                     const int* __restrict__ boffs,
                                                     int N, int NB, int E,
                                                     int* __restrict__ offs,
                                                     float* __restrict__ dinv,
                                                     int* __restrict__ csr) {
    __shared__ int cnt[1024];
    __shared__ int cur[1024];
    __shared__ int wsum[4];
    int t = threadIdx.x;
    int b = blockIdx.x;
    int node0 = b << 10;
    int nn = min(1024, N - node0);
    for (int i = t; i < nn; i += 256) cnt[i] = 0;
    __syncthreads();
    int e0 = boffs[b], e1 = boffs[b + 1];
    for (int e = e0 + t; e < e1; e += 256) atomicAdd(&cnt[ebuf[e].y - node0], 1);
    __syncthreads();
    int i0 = t * 4;
    int x[4];
#pragma unroll
    for (int j = 0; j < 4; ++j) x[j] = (i0 + j < nn) ? cnt[i0 + j] : 0;
    int tot = x[0] + x[1] + x[2] + x[3];
    int run = tot;
    int lane = t & 63, w = t >> 6;
#pragma unroll
    for (int off = 1; off < 64; off <<= 1) {
        int v = __shfl_up(run, off);
        if (lane >= off) run += v;
    }
    if (lane == 63) wsum[w] = run;
    __syncthreads();
    int base = 0;
    for (int u = 0; u < w; ++u) base += wsum[u];
    base += run - tot;
#pragma unroll
    for (int j = 0; j < 4; ++j) {
        if (i0 + j < nn) {
            int node = node0 + i0 + j;
            offs[node] = e0 + base;
            cur[i0 + j] = base;
            dinv[node] = rsqrtf((float)(x[j] + 1));
            base += x[j];
        }
    }
    __syncthreads();
    for (int e = e0 + t; e < e1; e += 256) {
        int2 rc = ebuf[e];
        int p = atomicAdd(&cur[rc.y - node0], 1);
        csr[e0 + p] = rc.x;
    }
    if (t == 0 && node0 + nn == N) offs[N] = E;
}

// ================= graph boundaries (batch is sorted) =================

__global__ __launch_bounds__(256) void k_bounds(const int* __restrict__ batch, int N,
                                                int G, int* __restrict__ gstart) {
    for (int i = blockIdx.x * blockDim.x + threadIdx.x; i < N;
         i += gridDim.x * blockDim.x) {
        int b = batch[i];
        int prev = (i == 0) ? -1 : batch[i - 1];
        for (int g = prev + 1; g <= b; ++g) gstart[g] = i;
        if (i == N - 1)
            for (int g = b + 1; g <= G; ++g) gstart[g] = N;
    }
}

// ================= weight convert+transpose: Wt[n][k] = bf16(W[k][n]) =================

__global__ void k_cvtW(const float* __restrict__ W, ushort* __restrict__ Wt, int K) {
    int o = blockIdx.x * 256 + threadIdx.x;
    if (o < 128 * K) {
        int n = o / K, k = o - n * K;
        Wt[o] = f2b(W[(size_t)k * 128 + n]);
    }
}

// ================= MFMA GEMM (2-deep pipelined): out = bf16((A@Wt^T)*dinv) =================
// A: fp32 [N][K] (ABF16=0, converted in staging) or bf16 [N][K] (ABF16=1).
// Wt: bf16 [128][K]. BM=128, BN=128, BK=64, 4 waves x 32 rows. NT = K/64 (compile-time).

template <int ABF16, int NT>
__global__ __launch_bounds__(256) void k_gemm_mfma(
    const void* __restrict__ Ap, const ushort* __restrict__ Wt,
    const float* __restrict__ dinv, ushort* __restrict__ outb, int N) {
    constexpr int K = NT * 64;
    __shared__ ushort As[128][72];
    __shared__ ushort Bs[128][72];
    const int tid = threadIdx.x;
    const int row0 = blockIdx.x * 128;
    const int w = tid >> 6, l = tid & 63;
    const int lr = l & 15, lk = l >> 4;
    f32x4 acc[2][8] = {};

    float4 pa[2][8];    // fp32 path prefetch sets
    uint4 pa4[2][4];    // bf16 path prefetch sets
    uint4 pb[2][4];

    auto loadA = [&](int kb, int s) {
        if constexpr (ABF16 == 0) {
            const float* A = (const float*)Ap;
#pragma unroll
            for (int u = 0; u < 8; ++u) {
                int ss = u * 256 + tid;
                int r = ss >> 4, c4 = ss & 15;
                int gr = row0 + r;
                pa[s][u] = make_float4(0.f, 0.f, 0.f, 0.f);
                if (gr < N) pa[s][u] = *(const float4*)(A + (size_t)gr * K + kb + c4 * 4);
            }
        } else {
            const ushort* A = (const ushort*)Ap;
#pragma unroll
            for (int u = 0; u < 4; ++u) {
                int ss = u * 256 + tid;
                int r = ss >> 3, c8 = ss & 7;
                int gr = row0 + r;
                pa4[s][u] = make_uint4(0u, 0u, 0u, 0u);
                if (gr < N) pa4[s][u] = *(const uint4*)(A + (size_t)gr * K + kb + c8 * 8);
            }
        }
    };
    auto loadB = [&](int kb, int s) {
#pragma unroll
        for (int u = 0; u < 4; ++u) {
            int ss = u * 256 + tid;
            int r = ss >> 3, c8 = ss & 7;
            pb[s][u] = *(const uint4*)(Wt + (size_t)r * K + kb + c8 * 8);
        }
    };
    auto store = [&](int s) {
        if constexpr (ABF16 == 0) {
#pragma unroll
            for (int u = 0; u < 8; ++u) {
                int ss = u * 256 + tid;
                int r = ss >> 4, c4 = ss & 15;
                ushort4 bb;
                bb.x = f2b(pa[s][u].x); bb.y = f2b(pa[s][u].y);
                bb.z = f2b(pa[s][u].z); bb.w = f2b(pa[s][u].w);
                *(ushort4*)&As[r][c4 * 4] = bb;
            }
        } else {
#pragma unroll
            for (int u = 0; u < 4; ++u) {
                int ss = u * 256 + tid;
                int r = ss >> 3, c8 = ss & 7;
                *(uint4*)&As[r][c8 * 8] = pa4[s][u];
            }
        }
#pragma unroll
        for (int u = 0; u < 4; ++u) {
            int ss = u * 256 + tid;
            int r = ss >> 3, c8 = ss & 7;
            *(uint4*)&Bs[r][c8 * 8] = pb[s][u];
        }
    };

    // prologue: 2 tiles' loads in flight
    loadA(0, 0); loadB(0, 0);
    if constexpr (NT > 1) { loadA(64, 1); loadB(64, 1); }
    store(0);
#pragma unroll
    for (int t = 0; t < NT; ++t) {
        __syncthreads();
        if (t + 2 < NT) { loadA((t + 2) * 64, t & 1); loadB((t + 2) * 64, t & 1); }
        const int wr0 = w * 32;
#pragma unroll
        for (int ks = 0; ks < 2; ++ks) {
            short8 a0 = *(const short8*)&As[wr0 + lr][ks * 32 + lk * 8];
            short8 a1 = *(const short8*)&As[wr0 + 16 + lr][ks * 32 + lk * 8];
#pragma unroll
            for (int nf = 0; nf < 8; ++nf) {
                short8 bf = *(const short8*)&Bs[nf * 16 + lr][ks * 32 + lk * 8];
                acc[0][nf] = __builtin_amdgcn_mfma_f32_16x16x32_bf16(a0, bf, acc[0][nf], 0, 0, 0);
                acc[1][nf] = __builtin_amdgcn_mfma_f32_16x16x32_bf16(a1, bf, acc[1][nf], 0, 0, 0);
            }
        }
        __syncthreads();
        if (t + 1 < NT) store((t + 1) & 1);
    }
#pragma unroll
    for (int mf = 0; mf < 2; ++mf) {
#pragma unroll
        for (int r = 0; r < 4; ++r) {
            int row = row0 + w * 32 + mf * 16 + lk * 4 + r;
            if (row < N) {
                float dv = dinv[row];
#pragma unroll
                for (int nf = 0; nf < 8; ++nf)
                    outb[(size_t)row * 128 + nf * 16 + lr] = f2b(acc[mf][nf][r] * dv);
            }
        }
    }
}

// ================= SpMM (bf16 in/out, fp32 accum): one wave per target node =================

__global__ __launch_bounds__(256) void k_spmm(
    const uint* __restrict__ hs, const int* __restrict__ csr,
    const int* __restrict__ offs, const float* __restrict__ dinv,
    const float* __restrict__ bias, uint* __restrict__ outb, int N) {
    int node = blockIdx.x * 4 + (threadIdx.x >> 6);
    int lane = threadIdx.x & 63;
    if (node >= N) return;
    int beg = offs[node], end = offs[node + 1];
    uint u0 = hs[(size_t)node * 64 + lane];  // self loop
    float ax = blo(u0), ay = bhi(u0);
    int i = beg;
    for (; i + 8 <= end; i += 8) {
        int rr[8];
#pragma unroll
        for (int j = 0; j < 8; ++j) rr[j] = csr[i + j];
        uint v[8];
#pragma unroll
        for (int j = 0; j < 8; ++j) v[j] = hs[(size_t)rr[j] * 64 + lane];
#pragma unroll
        for (int j = 0; j < 8; ++j) { ax += blo(v[j]); ay += bhi(v[j]); }
    }
    for (; i + 4 <= end; i += 4) {
        int r0 = csr[i], r1 = csr[i + 1], r2 = csr[i + 2], r3 = csr[i + 3];
        uint a = hs[(size_t)r0 * 64 + lane];
        uint b = hs[(size_t)r1 * 64 + lane];
        uint c = hs[(size_t)r2 * 64 + lane];
        uint d = hs[(size_t)r3 * 64 + lane];
        ax += (blo(a) + blo(b)) + (blo(c) + blo(d));
        ay += (bhi(a) + bhi(b)) + (bhi(c) + bhi(d));
    }
    for (; i < end; ++i) {
        uint a = hs[(size_t)csr[i] * 64 + lane];
        ax += blo(a); ay += bhi(a);
    }
    float dv = dinv[node];
    float2 bb = ((const float2*)bias)[lane];
    float ox = fmaxf(fmaf(ax, dv, bb.x), 0.f);
    float oy = fmaxf(fmaf(ay, dv, bb.y), 0.f);
    outb[(size_t)node * 64 + lane] = ((uint)f2b(oy) << 16) | (uint)f2b(ox);
}

// ================= pooling =================

__global__ void k_pool(const uint* __restrict__ h, const int* __restrict__ gstart,
                       float* __restrict__ psum, int G) {
    int g = blockIdx.x >> 3, sl = blockIdx.x & 7;
    int r0 = gstart[g], r1 = gstart[g + 1];
    int t = threadIdx.x;
    float sx = 0.f, sy = 0.f;
    for (int r = r0 + sl; r < r1; r += 8) {
        uint u = h[(size_t)r * 64 + t];
        sx += blo(u); sy += bhi(u);
    }
    atomicAdd(&psum[g * 128 + 2 * t], sx);
    atomicAdd(&psum[g * 128 + 2 * t + 1], sy);
}

__global__ void k_div(const float* __restrict__ psum, const int* __restrict__ gstart,
                      float* __restrict__ out, int total) {
    int i = blockIdx.x * blockDim.x + threadIdx.x;
    if (i < total) {
        int g = i >> 7;
        float c = (float)(gstart[g + 1] - gstart[g]);
        out[i] = psum[i] / fmaxf(c, 1.f);
    }
}

// ================= launch =================

extern "C" void kernel_launch(void* const* d_in, const int* in_sizes, int n_in,
                              void* d_out, int out_size, void* d_ws, size_t ws_size,
                              hipStream_t stream) {
    const float* x     = (const float*)d_in[0];
    const int*   ei    = (const int*)d_in[1];
    const int*   batch = (const int*)d_in[2];
    const float* W1    = (const float*)d_in[3];
    const float* b1    = (const float*)d_in[4];
    const float* W2    = (const float*)d_in[5];
    const float* b2    = (const float*)d_in[6];
    float* outp = (float*)d_out;

    const int N = in_sizes[2];
    const int E = in_sizes[1] / 2;
    const int D = in_sizes[0] / N;   // 512
    const int H = in_sizes[4];       // 128
    const int G = out_size / H;      // 64
    const int NB = (N + 1023) >> 10; // <= 128

    char* ws = (char*)d_ws;
    size_t off = 0;
    auto alloc = [&](size_t bytes) -> char* {
        char* p = ws + off;
        off = (off + bytes + 255) & ~(size_t)255;
        return p;
    };
    float*  dinv    = (float*)alloc((size_t)N * 4);
    int*    offs    = (int*)alloc((size_t)(N + 1) * 4);
    int*    gstart  = (int*)alloc((size_t)(G + 1) * 4);
    float*  psum    = (float*)alloc((size_t)G * H * 4);
    int*    bcnt    = (int*)alloc(128 * 4);
    int*    boffs   = (int*)alloc(132 * 4);
    int*    bcursor = (int*)alloc(128 * 4);
    ushort* wt1b    = (ushort*)alloc((size_t)H * D * 2);
    ushort* wt2b    = (ushort*)alloc((size_t)H * H * 2);
    int*    csr     = (int*)alloc((size_t)E * 4);
    char*   hbase   = alloc((size_t)N * H * 2 * 2);      // hb0 + hb1
    ushort* hb0     = (ushort*)hbase;
    ushort* hb1     = (ushort*)(hbase + (size_t)N * H * 2);
    int2*   ebuf    = (int2*)hbase;                      // transient alias (dead after sort)
    (void)ws_size; (void)n_in;

    hipMemsetAsync(bcnt, 0, 128 * 4, stream);
    hipMemsetAsync(psum, 0, (size_t)G * H * 4, stream);

    // CSR build
    k_bucket_hist<<<782, 256, 0, stream>>>(ei + E, E, NB, bcnt);
    k_scan_buckets<<<1, 128, 0, stream>>>(bcnt, NB, boffs, bcursor);
    k_bucket_scatter<<<(E + 2047) / 2048, 256, 0, stream>>>(ei, E, NB, bcursor, ebuf);
    k_bucket_sort<<<NB, 256, 0, stream>>>(ebuf, boffs, N, NB, E, offs, dinv, csr);

    k_bounds<<<(N + 255) / 256, 256, 0, stream>>>(batch, N, G, gstart);
    k_cvtW<<<(128 * D + 255) / 256, 256, 0, stream>>>(W1, wt1b, D);
    k_cvtW<<<(128 * H + 255) / 256, 256, 0, stream>>>(W2, wt2b, H);

    int gblocks = (N + 127) / 128;
    // layer 1 (K = 512 -> NT = 8)
    k_gemm_mfma<0, 8><<<gblocks, 256, 0, stream>>>(x, wt1b, dinv, hb0, N);
    k_spmm<<<(N + 3) / 4, 256, 0, stream>>>((const uint*)hb0, csr, offs, dinv, b1,
                                            (uint*)hb1, N);
    // layer 2 (K = 128 -> NT = 2)
    k_gemm_mfma<1, 2><<<gblocks, 256, 0, stream>>>(hb1, wt2b, dinv, hb0, N);
    k_spmm<<<(N + 3) / 4, 256, 0, stream>>>((const uint*)hb0, csr, offs, dinv, b2,
                                            (uint*)hb1, N);
    // pool
    k_pool<<<G * 8, 64, 0, stream>>>((const uint*)hb1, gstart, psum, G);
    k_div<<<(G * H + 255) / 256, 256, 0, stream>>>(psum, gstart, outp, G * H);
}

// Round 6
// 352.105 us; speedup vs baseline: 1.1943x; 1.1943x over previous
//
#include <hip/hip_runtime.h>
#include <hip/hip_bf16.h>

typedef __attribute__((ext_vector_type(8))) short short8;
typedef __attribute__((ext_vector_type(4))) float f32x4;

__device__ __forceinline__ ushort f2b(float f) {
    union { float f; uint u; } v; v.f = f;
    uint u = v.u;
    u += 0x7fffu + ((u >> 16) & 1u);   // RNE
    return (ushort)(u >> 16);
}
__device__ __forceinline__ float blo(uint u) { return __uint_as_float(u << 16); }
__device__ __forceinline__ float bhi(uint u) { return __uint_as_float(u & 0xffff0000u); }

// async global->LDS, 16B per lane; LDS dest = wave-uniform base + lane*16
__device__ __forceinline__ void gl_lds16(const void* g, void* s) {
    __builtin_amdgcn_global_load_lds(
        (const __attribute__((address_space(1))) void*)g,
        (__attribute__((address_space(3))) void*)s, 16, 0, 0);
}

// ================= CSR build: bucket counting sort =================
// bucket = node >> 10  (NB = ceil(N/1024) <= 128)

__global__ __launch_bounds__(256) void k_bucket_hist(const int* __restrict__ col, int E,
                                                     int NB, int* __restrict__ bcnt) {
    __shared__ int h[128];
    int tid = threadIdx.x;
    if (tid < 128) h[tid] = 0;
    __syncthreads();
    for (int e = blockIdx.x * blockDim.x + tid; e < E; e += gridDim.x * blockDim.x)
        atomicAdd(&h[col[e] >> 10], 1);
    __syncthreads();
    if (tid < NB && h[tid]) atomicAdd(&bcnt[tid], h[tid]);
}

// single block, 128 threads
__global__ void k_scan_buckets(const int* __restrict__ bcnt, int NB,
                               int* __restrict__ boffs, int* __restrict__ bcursor) {
    __shared__ int tmp[128];
    int t = threadIdx.x;
    int orig = (t < NB) ? bcnt[t] : 0;
    tmp[t] = orig;
    __syncthreads();
    for (int off = 1; off < 128; off <<= 1) {
        int v = (t >= off) ? tmp[t - off] : 0;
        __syncthreads();
        tmp[t] += v;
        __syncthreads();
    }
    if (t < NB) {
        int ex = tmp[t] - orig;
        boffs[t] = ex;
        bcursor[t] = ex;
    }
    if (t == 0) boffs[NB] = tmp[127];
}

// scatter edges into bucket-contiguous ebuf; per-block chunk reservation
__global__ __launch_bounds__(256) void k_bucket_scatter(const int* __restrict__ ei, int E,
                                                        int NB, int* __restrict__ bcursor,
                                                        int2* __restrict__ ebuf) {
    __shared__ int h[128], gb[128], lc[128];
    int tid = threadIdx.x;
    if (tid < 128) { h[tid] = 0; lc[tid] = 0; }
    __syncthreads();
    int e0 = blockIdx.x * 2048;
    int r[8], c[8], bk[8];
#pragma unroll
    for (int u = 0; u < 8; ++u) {
        int e = e0 + u * 256 + tid;
        if (e < E) {
            r[u] = ei[e];
            c[u] = ei[E + e];
            bk[u] = c[u] >> 10;
            atomicAdd(&h[bk[u]], 1);
        }
    }
    __syncthreads();
    if (tid < NB && h[tid]) gb[tid] = atomicAdd(&bcursor[tid], h[tid]);
    __syncthreads();
#pragma unroll
    for (int u = 0; u < 8; ++u) {
        int e = e0 + u * 256 + tid;
        if (e < E) {
            int p = gb[bk[u]] + atomicAdd(&lc[bk[u]], 1);
            ebuf[p] = make_int2(r[u], c[u]);
        }
    }
}

// one block per bucket: LDS counting sort -> csr, offs, dinv
__global__ __launch_bounds__(256) void k_bucket_sort(const int2* __restrict__ ebuf,
                                                     const int* __restrict__ boffs,
                                                     int N, int NB, int E,
                                                     int* __restrict__ offs,
                                                     float* __restrict__ dinv,
                                                     int* __restrict__ csr) {
    __shared__ int cnt[1024];
    __shared__ int cur[1024];
    __shared__ int wsum[4];
    int t = threadIdx.x;
    int b = blockIdx.x;
    int node0 = b << 10;
    int nn = min(1024, N - node0);
    for (int i = t; i < nn; i += 256) cnt[i] = 0;
    __syncthreads();
    int e0 = boffs[b], e1 = boffs[b + 1];
    for (int e = e0 + t; e < e1; e += 256) atomicAdd(&cnt[ebuf[e].y - node0], 1);
    __syncthreads();
    int i0 = t * 4;
    int x[4];
#pragma unroll
    for (int j = 0; j < 4; ++j) x[j] = (i0 + j < nn) ? cnt[i0 + j] : 0;
    int tot = x[0] + x[1] + x[2] + x[3];
    int run = tot;
    int lane = t & 63, w = t >> 6;
#pragma unroll
    for (int off = 1; off < 64; off <<= 1) {
        int v = __shfl_up(run, off);
        if (lane >= off) run += v;
    }
    if (lane == 63) wsum[w] = run;
    __syncthreads();
    int base = 0;
    for (int u = 0; u < w; ++u) base += wsum[u];
    base += run - tot;
#pragma unroll
    for (int j = 0; j < 4; ++j) {
        if (i0 + j < nn) {
            int node = node0 + i0 + j;
            offs[node] = e0 + base;
            cur[i0 + j] = base;
            dinv[node] = rsqrtf((float)(x[j] + 1));
            base += x[j];
        }
    }
    __syncthreads();
    for (int e = e0 + t; e < e1; e += 256) {
        int2 rc = ebuf[e];
        int p = atomicAdd(&cur[rc.y - node0], 1);
        csr[e0 + p] = rc.x;
    }
    if (t == 0 && node0 + nn == N) offs[N] = E;
}

// ================= graph boundaries (batch is sorted) =================

__global__ __launch_bounds__(256) void k_bounds(const int* __restrict__ batch, int N,
                                                int G, int* __restrict__ gstart) {
    for (int i = blockIdx.x * blockDim.x + threadIdx.x; i < N;
         i += gridDim.x * blockDim.x) {
        int b = batch[i];
        int prev = (i == 0) ? -1 : batch[i - 1];
        for (int g = prev + 1; g <= b; ++g) gstart[g] = i;
        if (i == N - 1)
            for (int g = b + 1; g <= G; ++g) gstart[g] = N;
    }
}

// ================= weight convert+transpose: Wt[n][k] = bf16(W[k][n]) =================

__global__ void k_cvtW(const float* __restrict__ W, ushort* __restrict__ Wt, int K) {
    int o = blockIdx.x * 256 + threadIdx.x;
    if (o < 128 * K) {
        int n = o / K, k = o - n * K;
        Wt[o] = f2b(W[(size_t)k * 128 + n]);
    }
}

// ================= MFMA GEMM (global_load_lds, m97 structure): out = bf16((A@Wt^T)*dinv) ===
// A: fp32 [N][K] (ABF16=0, staged fp32 in LDS, cvt at read) or bf16 [N][K] (ABF16=1).
// Wt: bf16 [128][K]. BM=128, BN=128, BK=64, 4 waves x 32 rows. NT = K/64.
// LDS layout: linear dest (gload_lds requirement) + XOR-swizzled SOURCE + swizzled READ.
//   A fp32 rows 256B: granule(16B) index ^= (row&15)   -> 4-way residual conflict
//   A/B bf16 rows 128B: granule index ^= (row&7)       -> 8-way residual conflict

template <int ABF16, int NT>
__global__ __launch_bounds__(256) void k_gemm_mfma(
    const void* __restrict__ Ap, const ushort* __restrict__ Wt,
    const float* __restrict__ dinv, ushort* __restrict__ outb, int N) {
    constexpr int K = NT * 64;
    constexpr int ASZ = ABF16 ? 128 * 64 * 2 : 128 * 64 * 4;
    __shared__ __align__(16) char asb[ASZ];
    __shared__ __align__(16) char bsb[128 * 64 * 2];
    const int tid = threadIdx.x;
    const int row0 = blockIdx.x * 128;
    const int w = tid >> 6, l = tid & 63;
    const int lr = l & 15, lk = l >> 4;
    f32x4 acc[2][8] = {};

    for (int t = 0; t < NT; ++t) {
        const int kb = t * 64;
        // ---- stage A ----
        if constexpr (ABF16 == 0) {
            const char* A = (const char*)Ap;
#pragma unroll
            for (int i = 0; i < 8; ++i) {
                int b = (w << 13) + (i << 10) + (l << 4);
                int r = b >> 8, cb = b & 255;
                int sb = cb ^ ((r & 15) << 4);
                int gr = row0 + r;
                if (gr < N)
                    gl_lds16(A + ((size_t)gr * K + kb) * 4 + sb,
                             asb + (w << 13) + (i << 10));
            }
        } else {
            const char* A = (const char*)Ap;
#pragma unroll
            for (int i = 0; i < 4; ++i) {
                int b = (w << 12) + (i << 10) + (l << 4);
                int r = b >> 7, cb = b & 127;
                int sb = cb ^ ((r & 7) << 4);
                int gr = row0 + r;
                if (gr < N)
                    gl_lds16(A + ((size_t)gr * K + kb) * 2 + sb,
                             asb + (w << 12) + (i << 10));
            }
        }
        // ---- stage B ----
#pragma unroll
        for (int i = 0; i < 4; ++i) {
            int b = (w << 12) + (i << 10) + (l << 4);
            int r = b >> 7, cb = b & 127;
            int sb = cb ^ ((r & 7) << 4);
            gl_lds16((const char*)Wt + ((size_t)r * K + kb) * 2 + sb,
                     bsb + (w << 12) + (i << 10));
        }
        __syncthreads();   // compiler drains vmcnt before s_barrier -> LDS ready
        // ---- MFMA ----
        const int wr0 = w * 32;
#pragma unroll
        for (int ks = 0; ks < 2; ++ks) {
            short8 a0, a1;
            const int r0 = wr0 + lr, r1 = wr0 + 16 + lr;
            if constexpr (ABF16 == 0) {
                const int c0 = ks * 128 + lk * 32;
                float4 v00 = *(const float4*)(asb + (r0 << 8) + ((c0) ^ ((r0 & 15) << 4)));
                float4 v01 = *(const float4*)(asb + (r0 << 8) + ((c0 + 16) ^ ((r0 & 15) << 4)));
                float4 v10 = *(const float4*)(asb + (r1 << 8) + ((c0) ^ ((r1 & 15) << 4)));
                float4 v11 = *(const float4*)(asb + (r1 << 8) + ((c0 + 16) ^ ((r1 & 15) << 4)));
                a0[0] = (short)f2b(v00.x); a0[1] = (short)f2b(v00.y);
                a0[2] = (short)f2b(v00.z); a0[3] = (short)f2b(v00.w);
                a0[4] = (short)f2b(v01.x); a0[5] = (short)f2b(v01.y);
                a0[6] = (short)f2b(v01.z); a0[7] = (short)f2b(v01.w);
                a1[0] = (short)f2b(v10.x); a1[1] = (short)f2b(v10.y);
                a1[2] = (short)f2b(v10.z); a1[3] = (short)f2b(v10.w);
                a1[4] = (short)f2b(v11.x); a1[5] = (short)f2b(v11.y);
                a1[6] = (short)f2b(v11.z); a1[7] = (short)f2b(v11.w);
            } else {
                const int c0 = ks * 64 + lk * 16;
                a0 = *(const short8*)(asb + (r0 << 7) + (c0 ^ ((r0 & 7) << 4)));
                a1 = *(const short8*)(asb + (r1 << 7) + (c0 ^ ((r1 & 7) << 4)));
            }
            const int c0b = ks * 64 + lk * 16;
#pragma unroll
            for (int nf = 0; nf < 8; ++nf) {
                const int nr = nf * 16 + lr;
                short8 bf = *(const short8*)(bsb + (nr << 7) + (c0b ^ ((nr & 7) << 4)));
                acc[0][nf] = __builtin_amdgcn_mfma_f32_16x16x32_bf16(a0, bf, acc[0][nf], 0, 0, 0);
                acc[1][nf] = __builtin_amdgcn_mfma_f32_16x16x32_bf16(a1, bf, acc[1][nf], 0, 0, 0);
            }
        }
        __syncthreads();   // all reads done before next stage overwrites
    }
#pragma unroll
    for (int mf = 0; mf < 2; ++mf) {
#pragma unroll
        for (int r = 0; r < 4; ++r) {
            int row = row0 + w * 32 + mf * 16 + (l >> 4) * 4 + r;
            if (row < N) {
                float dv = dinv[row];
#pragma unroll
                for (int nf = 0; nf < 8; ++nf)
                    outb[(size_t)row * 128 + nf * 16 + lr] = f2b(acc[mf][nf][r] * dv);
            }
        }
    }
}

// ================= SpMM (bf16 in/out, fp32 accum): one wave per target node =================

__global__ __launch_bounds__(256) void k_spmm(
    const uint* __restrict__ hs, const int* __restrict__ csr,
    const int* __restrict__ offs, const float* __restrict__ dinv,
    const float* __restrict__ bias, uint* __restrict__ outb, int N) {
    int node = blockIdx.x * 4 + (threadIdx.x >> 6);
    int lane = threadIdx.x & 63;
    if (node >= N) return;
    int beg = offs[node], end = offs[node + 1];
    uint u0 = hs[(size_t)node * 64 + lane];  // self loop
    float ax = blo(u0), ay = bhi(u0);
    int i = beg;
    for (; i + 8 <= end; i += 8) {
        int rr[8];
#pragma unroll
        for (int j = 0; j < 8; ++j) rr[j] = csr[i + j];
        uint v[8];
#pragma unroll
        for (int j = 0; j < 8; ++j) v[j] = hs[(size_t)rr[j] * 64 + lane];
#pragma unroll
        for (int j = 0; j < 8; ++j) { ax += blo(v[j]); ay += bhi(v[j]); }
    }
    for (; i + 4 <= end; i += 4) {
        int r0 = csr[i], r1 = csr[i + 1], r2 = csr[i + 2], r3 = csr[i + 3];
        uint a = hs[(size_t)r0 * 64 + lane];
        uint b = hs[(size_t)r1 * 64 + lane];
        uint c = hs[(size_t)r2 * 64 + lane];
        uint d = hs[(size_t)r3 * 64 + lane];
        ax += (blo(a) + blo(b)) + (blo(c) + blo(d));
        ay += (bhi(a) + bhi(b)) + (bhi(c) + bhi(d));
    }
    for (; i < end; ++i) {
        uint a = hs[(size_t)csr[i] * 64 + lane];
        ax += blo(a); ay += bhi(a);
    }
    float dv = dinv[node];
    float2 bb = ((const float2*)bias)[lane];
    float ox = fmaxf(fmaf(ax, dv, bb.x), 0.f);
    float oy = fmaxf(fmaf(ay, dv, bb.y), 0.f);
    outb[(size_t)node * 64 + lane] = ((uint)f2b(oy) << 16) | (uint)f2b(ox);
}

// ================= pooling =================

__global__ void k_pool(const uint* __restrict__ h, const int* __restrict__ gstart,
                       float* __restrict__ psum, int G) {
    int g = blockIdx.x >> 3, sl = blockIdx.x & 7;
    int r0 = gstart[g], r1 = gstart[g + 1];
    int t = threadIdx.x;
    float sx = 0.f, sy = 0.f;
    for (int r = r0 + sl; r < r1; r += 8) {
        uint u = h[(size_t)r * 64 + t];
        sx += blo(u); sy += bhi(u);
    }
    atomicAdd(&psum[g * 128 + 2 * t], sx);
    atomicAdd(&psum[g * 128 + 2 * t + 1], sy);
}

__global__ void k_div(const float* __restrict__ psum, const int* __restrict__ gstart,
                      float* __restrict__ out, int total) {
    int i = blockIdx.x * blockDim.x + threadIdx.x;
    if (i < total) {
        int g = i >> 7;
        float c = (float)(gstart[g + 1] - gstart[g]);
        out[i] = psum[i] / fmaxf(c, 1.f);
    }
}

// ================= launch =================

extern "C" void kernel_launch(void* const* d_in, const int* in_sizes, int n_in,
                              void* d_out, int out_size, void* d_ws, size_t ws_size,
                              hipStream_t stream) {
    const float* x     = (const float*)d_in[0];
    const int*   ei    = (const int*)d_in[1];
    const int*   batch = (const int*)d_in[2];
    const float* W1    = (const float*)d_in[3];
    const float* b1    = (const float*)d_in[4];
    const float* W2    = (const float*)d_in[5];
    const float* b2    = (const float*)d_in[6];
    float* outp = (float*)d_out;

    const int N = in_sizes[2];
    const int E = in_sizes[1] / 2;
    const int D = in_sizes[0] / N;   // 512
    const int H = in_sizes[4];       // 128
    const int G = out_size / H;      // 64
    const int NB = (N + 1023) >> 10; // <= 128

    char* ws = (char*)d_ws;
    size_t off = 0;
    auto alloc = [&](size_t bytes) -> char* {
        char* p = ws + off;
        off = (off + bytes + 255) & ~(size_t)255;
        return p;
    };
    float*  dinv    = (float*)alloc((size_t)N * 4);
    int*    offs    = (int*)alloc((size_t)(N + 1) * 4);
    int*    gstart  = (int*)alloc((size_t)(G + 1) * 4);
    float*  psum    = (float*)alloc((size_t)G * H * 4);
    int*    bcnt    = (int*)alloc(128 * 4);
    int*    boffs   = (int*)alloc(132 * 4);
    int*    bcursor = (int*)alloc(128 * 4);
    ushort* wt1b    = (ushort*)alloc((size_t)H * D * 2);
    ushort* wt2b    = (ushort*)alloc((size_t)H * H * 2);
    int*    csr     = (int*)alloc((size_t)E * 4);
    char*   hbase   = alloc((size_t)N * H * 2 * 2);      // hb0 + hb1
    ushort* hb0     = (ushort*)hbase;
    ushort* hb1     = (ushort*)(hbase + (size_t)N * H * 2);
    int2*   ebuf    = (int2*)hbase;                      // transient alias (dead after sort)
    (void)ws_size; (void)n_in;

    hipMemsetAsync(bcnt, 0, 128 * 4, stream);
    hipMemsetAsync(psum, 0, (size_t)G * H * 4, stream);

    // CSR build
    k_bucket_hist<<<782, 256, 0, stream>>>(ei + E, E, NB, bcnt);
    k_scan_buckets<<<1, 128, 0, stream>>>(bcnt, NB, boffs, bcursor);
    k_bucket_scatter<<<(E + 2047) / 2048, 256, 0, stream>>>(ei, E, NB, bcursor, ebuf);
    k_bucket_sort<<<NB, 256, 0, stream>>>(ebuf, boffs, N, NB, E, offs, dinv, csr);

    k_bounds<<<(N + 255) / 256, 256, 0, stream>>>(batch, N, G, gstart);
    k_cvtW<<<(128 * D + 255) / 256, 256, 0, stream>>>(W1, wt1b, D);
    k_cvtW<<<(128 * H + 255) / 256, 256, 0, stream>>>(W2, wt2b, H);

    int gblocks = (N + 127) / 128;
    // layer 1 (K = 512 -> NT = 8)
    k_gemm_mfma<0, 8><<<gblocks, 256, 0, stream>>>(x, wt1b, dinv, hb0, N);
    k_spmm<<<(N + 3) / 4, 256, 0, stream>>>((const uint*)hb0, csr, offs, dinv, b1,
                                            (uint*)hb1, N);
    // layer 2 (K = 128 -> NT = 2)
    k_gemm_mfma<1, 2><<<gblocks, 256, 0, stream>>>(hb1, wt2b, dinv, hb0, N);
    k_spmm<<<(N + 3) / 4, 256, 0, stream>>>((const uint*)hb0, csr, offs, dinv, b2,
                                            (uint*)hb1, N);
    // pool
    k_pool<<<G * 8, 64, 0, stream>>>((const uint*)hb1, gstart, psum, G);
    k_div<<<(G * H + 255) / 256, 256, 0, stream>>>(psum, gstart, outp, G * H);
}

// Round 7
// 334.776 us; speedup vs baseline: 1.2562x; 1.0518x over previous
//
#include <hip/hip_runtime.h>
#include <hip/hip_bf16.h>

typedef __attribute__((ext_vector_type(8))) short short8;
typedef __attribute__((ext_vector_type(4))) float f32x4;

__device__ __forceinline__ ushort f2b(float f) {
    union { float f; uint u; } v; v.f = f;
    uint u = v.u;
    u += 0x7fffu + ((u >> 16) & 1u);   // RNE
    return (ushort)(u >> 16);
}
__device__ __forceinline__ float blo(uint u) { return __uint_as_float(u << 16); }
__device__ __forceinline__ float bhi(uint u) { return __uint_as_float(u & 0xffff0000u); }

// async global->LDS, 16B per lane; LDS dest = wave-uniform base + lane*16
__device__ __forceinline__ void gl_lds16(const void* g, void* s) {
    __builtin_amdgcn_global_load_lds(
        (const __attribute__((address_space(1))) void*)g,
        (__attribute__((address_space(3))) void*)s, 16, 0, 0);
}

// ================= fused setup: cvt W1/W2 (transpose to [128][K]), bounds, zeros ==========

__global__ __launch_bounds__(256) void k_setup(
    const float* __restrict__ W1, ushort* __restrict__ wt1b, int D,
    const float* __restrict__ W2, ushort* __restrict__ wt2b, int H,
    const int* __restrict__ batch, int N, int G, int* __restrict__ gstart,
    int* __restrict__ bcnt, float* __restrict__ psum, uint* __restrict__ hb0zrow,
    int c1b, int c2b, int bb) {
    int b = blockIdx.x, t = threadIdx.x;
    if (b < c1b) {
        int o = b * 256 + t;
        if (o < 128 * D) {
            int n = o / D, k = o - n * D;
            wt1b[o] = f2b(W1[(size_t)k * 128 + n]);
        }
    } else if (b < c1b + c2b) {
        int o = (b - c1b) * 256 + t;
        if (o < 128 * H) {
            int n = o / H, k = o - n * H;
            wt2b[o] = f2b(W2[(size_t)k * 128 + n]);
        }
    } else if (b < c1b + c2b + bb) {
        int i = (b - c1b - c2b) * 256 + t;
        if (i < N) {
            int bt = batch[i];
            int prev = (i == 0) ? -1 : batch[i - 1];
            for (int g = prev + 1; g <= bt; ++g) gstart[g] = i;
            if (i == N - 1)
                for (int g = bt + 1; g <= G; ++g) gstart[g] = N;
        }
    } else {
        // zero: psum (G*H), bcnt (128), hb0 zero row (64 uints)
        int total = G * H + 128 + 64;
        for (int i = t; i < total; i += 256) {
            if (i < G * H) psum[i] = 0.f;
            else if (i < G * H + 128) bcnt[i - G * H] = 0;
            else hb0zrow[i - G * H - 128] = 0u;
        }
    }
}

// ================= CSR build: bucket counting sort =================
// bucket = node >> 10  (NB = ceil(N/1024) <= 128)

__global__ __launch_bounds__(256) void k_bucket_hist(const int* __restrict__ col, int E,
                                                     int NB, int* __restrict__ bcnt) {
    __shared__ int h[128];
    int tid = threadIdx.x;
    if (tid < 128) h[tid] = 0;
    __syncthreads();
    for (int e = blockIdx.x * blockDim.x + tid; e < E; e += gridDim.x * blockDim.x)
        atomicAdd(&h[col[e] >> 10], 1);
    __syncthreads();
    if (tid < NB && h[tid]) atomicAdd(&bcnt[tid], h[tid]);
}

// single block, 128 threads
__global__ void k_scan_buckets(const int* __restrict__ bcnt, int NB,
                               int* __restrict__ boffs, int* __restrict__ bcursor) {
    __shared__ int tmp[128];
    int t = threadIdx.x;
    int orig = (t < NB) ? bcnt[t] : 0;
    tmp[t] = orig;
    __syncthreads();
    for (int off = 1; off < 128; off <<= 1) {
        int v = (t >= off) ? tmp[t - off] : 0;
        __syncthreads();
        tmp[t] += v;
        __syncthreads();
    }
    if (t < NB) {
        int ex = tmp[t] - orig;
        boffs[t] = ex;
        bcursor[t] = ex;
    }
    if (t == 0) boffs[NB] = tmp[127];
}

// scatter edges into bucket-contiguous ebuf (packed: (local_tgt<<22)|src, N < 4M)
__global__ __launch_bounds__(256) void k_bucket_scatter(const int* __restrict__ ei, int E,
                                                        int NB, int* __restrict__ bcursor,
                                                        uint* __restrict__ ebuf) {
    __shared__ int h[128], gb[128], lc[128];
    int tid = threadIdx.x;
    if (tid < 128) { h[tid] = 0; lc[tid] = 0; }
    __syncthreads();
    int e0 = blockIdx.x * 2048;
    int r[8], c[8], bk[8];
#pragma unroll
    for (int u = 0; u < 8; ++u) {
        int e = e0 + u * 256 + tid;
        if (e < E) {
            r[u] = ei[e];
            c[u] = ei[E + e];
            bk[u] = c[u] >> 10;
            atomicAdd(&h[bk[u]], 1);
        }
    }
    __syncthreads();
    if (tid < NB && h[tid]) gb[tid] = atomicAdd(&bcursor[tid], h[tid]);
    __syncthreads();
#pragma unroll
    for (int u = 0; u < 8; ++u) {
        int e = e0 + u * 256 + tid;
        if (e < E) {
            int p = gb[bk[u]] + atomicAdd(&lc[bk[u]], 1);
            ebuf[p] = ((uint)(c[u] & 1023) << 22) | (uint)r[u];
        }
    }
}

// one block per bucket: LDS counting sort -> padded csr, packed offs, dinv.
// csr region for bucket b starts at boffs[b] + b*8192 (8 pad slots per node max).
// Per-node slot = align8(deg), padding entries point at row N (zeroed).
// offs[node] = (padded_begin << 10) | deg.

__global__ __launch_bounds__(256) void k_bucket_sort(const uint* __restrict__ ebuf,
                                                     const int* __restrict__ boffs,
                                                     int N, int NB, int E,
                                                     uint* __restrict__ offs,
                                                     float* __restrict__ dinv,
                                                     int* __restrict__ csr) {
    __shared__ int cnt[1024];
    __shared__ int cur[1024];
    __shared__ int wsum[4];
    int t = threadIdx.x;
    int b = blockIdx.x;
    int node0 = b << 10;
    int nn = min(1024, N - node0);
    for (int i = t; i < nn; i += 256) cnt[i] = 0;
    __syncthreads();
    int e0 = boffs[b], e1 = boffs[b + 1];
    int e0p = e0 + b * 8192;
    for (int e = e0 + t; e < e1; e += 256) atomicAdd(&cnt[ebuf[e] >> 22], 1);
    __syncthreads();
    int i0 = t * 4;
    int x[4], px[4];
#pragma unroll
    for (int j = 0; j < 4; ++j) {
        x[j] = (i0 + j < nn) ? cnt[i0 + j] : 0;
        px[j] = (x[j] + 7) & ~7;
    }
    int tot = px[0] + px[1] + px[2] + px[3];
    int run = tot;
    int lane = t & 63, w = t >> 6;
#pragma unroll
    for (int off = 1; off < 64; off <<= 1) {
        int v = __shfl_up(run, off);
        if (lane >= off) run += v;
    }
    if (lane == 63) wsum[w] = run;
    __syncthreads();
    int base = 0;
    for (int u = 0; u < w; ++u) base += wsum[u];
    base += run - tot;
#pragma unroll
    for (int j = 0; j < 4; ++j) {
        if (i0 + j < nn) {
            int node = node0 + i0 + j;
            offs[node] = ((uint)(e0p + base) << 10) | (uint)x[j];
            cur[i0 + j] = base;
            dinv[node] = rsqrtf((float)(x[j] + 1));
            for (int k = x[j]; k < px[j]; ++k) csr[e0p + base + k] = N;  // pad -> zero row
            base += px[j];
        }
    }
    __syncthreads();
    for (int e = e0 + t; e < e1; e += 256) {
        uint v = ebuf[e];
        int p = atomicAdd(&cur[v >> 22], 1);
        csr[e0p + p] = (int)(v & 0x3FFFFFu);
    }
}

// ================= MFMA GEMM (global_load_lds, m97 structure): out = bf16((A@Wt^T)*dinv) ===

template <int ABF16, int NT>
__global__ __launch_bounds__(256) void k_gemm_mfma(
    const void* __restrict__ Ap, const ushort* __restrict__ Wt,
    const float* __restrict__ dinv, ushort* __restrict__ outb, int N) {
    constexpr int K = NT * 64;
    constexpr int ASZ = ABF16 ? 128 * 64 * 2 : 128 * 64 * 4;
    __shared__ __align__(16) char asb[ASZ];
    __shared__ __align__(16) char bsb[128 * 64 * 2];
    const int tid = threadIdx.x;
    const int row0 = blockIdx.x * 128;
    const int w = tid >> 6, l = tid & 63;
    const int lr = l & 15, lk = l >> 4;
    f32x4 acc[2][8] = {};

    for (int t = 0; t < NT; ++t) {
        const int kb = t * 64;
        if constexpr (ABF16 == 0) {
            const char* A = (const char*)Ap;
#pragma unroll
            for (int i = 0; i < 8; ++i) {
                int b = (w << 13) + (i << 10) + (l << 4);
                int r = b >> 8, cb = b & 255;
                int sb = cb ^ ((r & 15) << 4);
                int gr = row0 + r;
                if (gr < N)
                    gl_lds16(A + ((size_t)gr * K + kb) * 4 + sb,
                             asb + (w << 13) + (i << 10));
            }
        } else {
            const char* A = (const char*)Ap;
#pragma unroll
            for (int i = 0; i < 4; ++i) {
                int b = (w << 12) + (i << 10) + (l << 4);
                int r = b >> 7, cb = b & 127;
                int sb = cb ^ ((r & 7) << 4);
                int gr = row0 + r;
                if (gr < N)
                    gl_lds16(A + ((size_t)gr * K + kb) * 2 + sb,
                             asb + (w << 12) + (i << 10));
            }
        }
#pragma unroll
        for (int i = 0; i < 4; ++i) {
            int b = (w << 12) + (i << 10) + (l << 4);
            int r = b >> 7, cb = b & 127;
            int sb = cb ^ ((r & 7) << 4);
            gl_lds16((const char*)Wt + ((size_t)r * K + kb) * 2 + sb,
                     bsb + (w << 12) + (i << 10));
        }
        __syncthreads();
        const int wr0 = w * 32;
#pragma unroll
        for (int ks = 0; ks < 2; ++ks) {
            short8 a0, a1;
            const int r0 = wr0 + lr, r1 = wr0 + 16 + lr;
            if constexpr (ABF16 == 0) {
                const int c0 = ks * 128 + lk * 32;
                float4 v00 = *(const float4*)(asb + (r0 << 8) + ((c0) ^ ((r0 & 15) << 4)));
                float4 v01 = *(const float4*)(asb + (r0 << 8) + ((c0 + 16) ^ ((r0 & 15) << 4)));
                float4 v10 = *(const float4*)(asb + (r1 << 8) + ((c0) ^ ((r1 & 15) << 4)));
                float4 v11 = *(const float4*)(asb + (r1 << 8) + ((c0 + 16) ^ ((r1 & 15) << 4)));
                a0[0] = (short)f2b(v00.x); a0[1] = (short)f2b(v00.y);
                a0[2] = (short)f2b(v00.z); a0[3] = (short)f2b(v00.w);
                a0[4] = (short)f2b(v01.x); a0[5] = (short)f2b(v01.y);
                a0[6] = (short)f2b(v01.z); a0[7] = (short)f2b(v01.w);
                a1[0] = (short)f2b(v10.x); a1[1] = (short)f2b(v10.y);
                a1[2] = (short)f2b(v10.z); a1[3] = (short)f2b(v10.w);
                a1[4] = (short)f2b(v11.x); a1[5] = (short)f2b(v11.y);
                a1[6] = (short)f2b(v11.z); a1[7] = (short)f2b(v11.w);
            } else {
                const int c0 = ks * 64 + lk * 16;
                a0 = *(const short8*)(asb + (r0 << 7) + (c0 ^ ((r0 & 7) << 4)));
                a1 = *(const short8*)(asb + (r1 << 7) + (c0 ^ ((r1 & 7) << 4)));
            }
            const int c0b = ks * 64 + lk * 16;
#pragma unroll
            for (int nf = 0; nf < 8; ++nf) {
                const int nr = nf * 16 + lr;
                short8 bf = *(const short8*)(bsb + (nr << 7) + (c0b ^ ((nr & 7) << 4)));
                acc[0][nf] = __builtin_amdgcn_mfma_f32_16x16x32_bf16(a0, bf, acc[0][nf], 0, 0, 0);
                acc[1][nf] = __builtin_amdgcn_mfma_f32_16x16x32_bf16(a1, bf, acc[1][nf], 0, 0, 0);
            }
        }
        __syncthreads();
    }
#pragma unroll
    for (int mf = 0; mf < 2; ++mf) {
#pragma unroll
        for (int r = 0; r < 4; ++r) {
            int row = row0 + w * 32 + mf * 16 + lk * 4 + r;
            if (row < N) {
                float dv = dinv[row];
#pragma unroll
                for (int nf = 0; nf < 8; ++nf)
                    outb[(size_t)row * 128 + nf * 16 + lr] = f2b(acc[mf][nf][r] * dv);
            }
        }
    }
}

// ================= SpMM: 2 edges/instruction, half-wave per row, padded CSR =================
// hs2: bf16 rows as uint2[32] (256B). Row N is all-zero (padding target).
// offs packed: (padded_begin << 10) | deg.

__global__ __launch_bounds__(256) void k_spmm(
    const uint2* __restrict__ hs2, const int* __restrict__ csr,
    const uint* __restrict__ offs, const float* __restrict__ dinv,
    const float* __restrict__ bias, uint2* __restrict__ outb, int N) {
    int node = blockIdx.x * 4 + (threadIdx.x >> 6);
    if (node >= N) return;
    int l = threadIdx.x & 63, hl = l & 31;
    const bool hi = l >= 32;
    uint pv = offs[node];
    int beg = (int)(pv >> 10), deg = (int)(pv & 1023u);
    int pend = beg + ((deg + 7) & ~7);
    float a0 = 0.f, a1 = 0.f, a2 = 0.f, a3 = 0.f;
    if (!hi) {  // self loop (lo half only; hi half contributes 0)
        uint2 s = hs2[(size_t)node * 32 + hl];
        a0 = blo(s.x); a1 = bhi(s.x); a2 = blo(s.y); a3 = bhi(s.y);
    }
    int i = beg;
    for (; i + 16 <= pend; i += 16) {      // 8 gathers in flight, 16 edges
        uint2 v[8];
#pragma unroll
        for (int j = 0; j < 8; ++j) {
            int ea = csr[i + 2 * j], eb = csr[i + 2 * j + 1];
            int src = hi ? eb : ea;
            v[j] = hs2[(size_t)src * 32 + hl];
        }
#pragma unroll
        for (int j = 0; j < 8; ++j) {
            a0 += blo(v[j].x); a1 += bhi(v[j].x);
            a2 += blo(v[j].y); a3 += bhi(v[j].y);
        }
    }
    for (; i < pend; i += 8) {             // 4 gathers, 8 edges
        uint2 v[4];
#pragma unroll
        for (int j = 0; j < 4; ++j) {
            int ea = csr[i + 2 * j], eb = csr[i + 2 * j + 1];
            int src = hi ? eb : ea;
            v[j] = hs2[(size_t)src * 32 + hl];
        }
#pragma unroll
        for (int j = 0; j < 4; ++j) {
            a0 += blo(v[j].x); a1 += bhi(v[j].x);
            a2 += blo(v[j].y); a3 += bhi(v[j].y);
        }
    }
    a0 += __shfl_xor(a0, 32);
    a1 += __shfl_xor(a1, 32);
    a2 += __shfl_xor(a2, 32);
    a3 += __shfl_xor(a3, 32);
    if (!hi) {
        float dv = dinv[node];
        float4 bb = ((const float4*)bias)[hl];
        float o0 = fmaxf(fmaf(a0, dv, bb.x), 0.f);
        float o1 = fmaxf(fmaf(a1, dv, bb.y), 0.f);
        float o2 = fmaxf(fmaf(a2, dv, bb.z), 0.f);
        float o3 = fmaxf(fmaf(a3, dv, bb.w), 0.f);
        uint2 o;
        o.x = ((uint)f2b(o1) << 16) | (uint)f2b(o0);
        o.y = ((uint)f2b(o3) << 16) | (uint)f2b(o2);
        outb[(size_t)node * 32 + hl] = o;
    }
}

// ================= pooling =================

__global__ void k_pool(const uint* __restrict__ h, const int* __restrict__ gstart,
                       float* __restrict__ psum, int G) {
    int g = blockIdx.x >> 3, sl = blockIdx.x & 7;
    int r0 = gstart[g], r1 = gstart[g + 1];
    int t = threadIdx.x;
    float sx = 0.f, sy = 0.f;
    for (int r = r0 + sl; r < r1; r += 8) {
        uint u = h[(size_t)r * 64 + t];
        sx += blo(u); sy += bhi(u);
    }
    atomicAdd(&psum[g * 128 + 2 * t], sx);
    atomicAdd(&psum[g * 128 + 2 * t + 1], sy);
}

__global__ void k_div(const float* __restrict__ psum, const int* __restrict__ gstart,
                      float* __restrict__ out, int total) {
    int i = blockIdx.x * blockDim.x + threadIdx.x;
    if (i < total) {
        int g = i >> 7;
        float c = (float)(gstart[g + 1] - gstart[g]);
        out[i] = psum[i] / fmaxf(c, 1.f);
    }
}

// ================= launch =================

extern "C" void kernel_launch(void* const* d_in, const int* in_sizes, int n_in,
                              void* d_out, int out_size, void* d_ws, size_t ws_size,
                              hipStream_t stream) {
    const float* x     = (const float*)d_in[0];
    const int*   ei    = (const int*)d_in[1];
    const int*   batch = (const int*)d_in[2];
    const float* W1    = (const float*)d_in[3];
    const float* b1    = (const float*)d_in[4];
    const float* W2    = (const float*)d_in[5];
    const float* b2    = (const float*)d_in[6];
    float* outp = (float*)d_out;

    const int N = in_sizes[2];
    const int E = in_sizes[1] / 2;
    const int D = in_sizes[0] / N;   // 512
    const int H = in_sizes[4];       // 128
    const int G = out_size / H;      // 64
    const int NB = (N + 1023) >> 10; // <= 128

    char* ws = (char*)d_ws;
    size_t off = 0;
    auto alloc = [&](size_t bytes) -> char* {
        char* p = ws + off;
        off = (off + bytes + 255) & ~(size_t)255;
        return p;
    };
    float*  dinv    = (float*)alloc((size_t)N * 4);
    uint*   offs    = (uint*)alloc((size_t)N * 4);
    int*    gstart  = (int*)alloc((size_t)(G + 1) * 4);
    float*  psum    = (float*)alloc((size_t)G * H * 4);
    int*    bcnt    = (int*)alloc(128 * 4);
    int*    boffs   = (int*)alloc(132 * 4);
    int*    bcursor = (int*)alloc(128 * 4);
    ushort* wt1b    = (ushort*)alloc((size_t)H * D * 2);
    ushort* wt2b    = (ushort*)alloc((size_t)H * H * 2);
    int*    csr     = (int*)alloc(((size_t)E + (size_t)NB * 8192) * 4);  // padded
    char*   hbase   = alloc(((size_t)N * 2 + 8) * H * 2);   // hb0 (+zero row) + hb1
    ushort* hb0     = (ushort*)hbase;
    ushort* hb1     = (ushort*)(hbase + ((size_t)N + 8) * H * 2);
    uint*   ebuf    = (uint*)hbase;                          // transient alias
    (void)ws_size; (void)n_in;

    int c1b = (128 * D + 255) / 256;
    int c2b = (128 * H + 255) / 256;
    int bb  = (N + 255) / 256;

    k_setup<<<c1b + c2b + bb + 1, 256, 0, stream>>>(
        W1, wt1b, D, W2, wt2b, H, batch, N, G, gstart, bcnt, psum,
        (uint*)(hb0 + (size_t)N * H), c1b, c2b, bb);

    // CSR build
    k_bucket_hist<<<782, 256, 0, stream>>>(ei + E, E, NB, bcnt);
    k_scan_buckets<<<1, 128, 0, stream>>>(bcnt, NB, boffs, bcursor);
    k_bucket_scatter<<<(E + 2047) / 2048, 256, 0, stream>>>(ei, E, NB, bcursor, ebuf);
    k_bucket_sort<<<NB, 256, 0, stream>>>(ebuf, boffs, N, NB, E, offs, dinv, csr);

    int gblocks = (N + 127) / 128;
    // layer 1 (K = 512 -> NT = 8)
    k_gemm_mfma<0, 8><<<gblocks, 256, 0, stream>>>(x, wt1b, dinv, hb0, N);
    k_spmm<<<(N + 3) / 4, 256, 0, stream>>>((const uint2*)hb0, csr, offs, dinv, b1,
                                            (uint2*)hb1, N);
    // layer 2 (K = 128 -> NT = 2)
    k_gemm_mfma<1, 2><<<gblocks, 256, 0, stream>>>(hb1, wt2b, dinv, hb0, N);
    k_spmm<<<(N + 3) / 4, 256, 0, stream>>>((const uint2*)hb0, csr, offs, dinv, b2,
                                            (uint2*)hb1, N);
    // pool
    k_pool<<<G * 8, 64, 0, stream>>>((const uint*)hb1, gstart, psum, G);
    k_div<<<(G * H + 255) / 256, 256, 0, stream>>>(psum, gstart, outp, G * H);
}

// Round 8
// 324.009 us; speedup vs baseline: 1.2979x; 1.0332x over previous
//
#include <hip/hip_runtime.h>
#include <hip/hip_bf16.h>

typedef __attribute__((ext_vector_type(8))) short short8;
typedef __attribute__((ext_vector_type(4))) float f32x4;

__device__ __forceinline__ ushort f2b(float f) {
    union { float f; uint u; } v; v.f = f;
    uint u = v.u;
    u += 0x7fffu + ((u >> 16) & 1u);   // RNE
    return (ushort)(u >> 16);
}
__device__ __forceinline__ float blo(uint u) { return __uint_as_float(u << 16); }
__device__ __forceinline__ float bhi(uint u) { return __uint_as_float(u & 0xffff0000u); }

// async global->LDS, 16B per lane; LDS dest = wave-uniform base + lane*16
__device__ __forceinline__ void gl_lds16(const void* g, void* s) {
    __builtin_amdgcn_global_load_lds(
        (const __attribute__((address_space(1))) void*)g,
        (__attribute__((address_space(3))) void*)s, 16, 0, 0);
}

#define ECAP 32768   // ebuf slots per bucket
#define CCAP 40960   // csr slots per bucket (ECAP + 8K pad)

// ================= fused setup: cvt W1/W2 (transpose to [128][K]), bounds, zeros ==========

__global__ __launch_bounds__(256) void k_setup(
    const float* __restrict__ W1, ushort* __restrict__ wt1b, int D,
    const float* __restrict__ W2, ushort* __restrict__ wt2b, int H,
    const int* __restrict__ batch, int N, int G, int* __restrict__ gstart,
    int* __restrict__ bcur, float* __restrict__ psum, uint* __restrict__ hb0zrow,
    int c1b, int c2b, int bb) {
    int b = blockIdx.x, t = threadIdx.x;
    if (b < c1b) {
        int o = b * 256 + t;
        if (o < 128 * D) {
            int n = o / D, k = o - n * D;
            wt1b[o] = f2b(W1[(size_t)k * 128 + n]);
        }
    } else if (b < c1b + c2b) {
        int o = (b - c1b) * 256 + t;
        if (o < 128 * H) {
            int n = o / H, k = o - n * H;
            wt2b[o] = f2b(W2[(size_t)k * 128 + n]);
        }
    } else if (b < c1b + c2b + bb) {
        int i = (b - c1b - c2b) * 256 + t;
        if (i < N) {
            int bt = batch[i];
            int prev = (i == 0) ? -1 : batch[i - 1];
            for (int g = prev + 1; g <= bt; ++g) gstart[g] = i;
            if (i == N - 1)
                for (int g = bt + 1; g <= G; ++g) gstart[g] = N;
        }
    } else {
        // zero: psum (G*H), bcur (128), hb0 zero row (64 uints)
        int total = G * H + 128 + 64;
        for (int i = t; i < total; i += 256) {
            if (i < G * H) psum[i] = 0.f;
            else if (i < G * H + 128) bcur[i - G * H] = 0;
            else hb0zrow[i - G * H - 128] = 0u;
        }
    }
}

// ================= CSR build (2 kernels, fixed-capacity buckets) =================
// bucket = node >> 10  (NB = ceil(N/1024) <= 128)

// scatter edges into per-bucket fixed regions (packed: (local_tgt<<22)|src, N < 4M)
__global__ __launch_bounds__(256) void k_bucket_scatter(const int* __restrict__ ei, int E,
                                                        int NB, int* __restrict__ bcur,
                                                        uint* __restrict__ ebuf) {
    __shared__ int h[128], gb[128], lc[128];
    int tid = threadIdx.x;
    if (tid < 128) { h[tid] = 0; lc[tid] = 0; }
    __syncthreads();
    int e0 = blockIdx.x * 2048;
    int r[8], c[8], bk[8];
#pragma unroll
    for (int u = 0; u < 8; ++u) {
        int e = e0 + u * 256 + tid;
        if (e < E) {
            r[u] = ei[e];
            c[u] = ei[E + e];
            bk[u] = c[u] >> 10;
            atomicAdd(&h[bk[u]], 1);
        }
    }
    __syncthreads();
    if (tid < NB && h[tid]) gb[tid] = atomicAdd(&bcur[tid], h[tid]);
    __syncthreads();
#pragma unroll
    for (int u = 0; u < 8; ++u) {
        int e = e0 + u * 256 + tid;
        if (e < E) {
            int p = gb[bk[u]] + atomicAdd(&lc[bk[u]], 1);
            ebuf[(size_t)bk[u] * ECAP + p] = ((uint)(c[u] & 1023) << 22) | (uint)r[u];
        }
    }
}

// one block per bucket: LDS counting sort -> padded csr, packed offs, dinv.
// csr region for bucket b is [b*CCAP, ...). Per-node slot = align8(deg);
// padding entries point at row N (zeroed). offs[node] = (begin << 10) | deg.
__global__ __launch_bounds__(256) void k_bucket_sort(const uint* __restrict__ ebuf,
                                                     const int* __restrict__ bcur,
                                                     int N, int NB,
                                                     uint* __restrict__ offs,
                                                     float* __restrict__ dinv,
                                                     int* __restrict__ csr) {
    __shared__ int cnt[1024];
    __shared__ int cur[1024];
    __shared__ int wsum[4];
    int t = threadIdx.x;
    int b = blockIdx.x;
    int node0 = b << 10;
    int nn = min(1024, N - node0);
    for (int i = t; i < nn; i += 256) cnt[i] = 0;
    __syncthreads();
    int e0 = b * ECAP, e1 = e0 + bcur[b];
    int e0p = b * CCAP;
    for (int e = e0 + t; e < e1; e += 256) atomicAdd(&cnt[ebuf[e] >> 22], 1);
    __syncthreads();
    int i0 = t * 4;
    int x[4], px[4];
#pragma unroll
    for (int j = 0; j < 4; ++j) {
        x[j] = (i0 + j < nn) ? cnt[i0 + j] : 0;
        px[j] = (x[j] + 7) & ~7;
    }
    int tot = px[0] + px[1] + px[2] + px[3];
    int run = tot;
    int lane = t & 63, w = t >> 6;
#pragma unroll
    for (int off = 1; off < 64; off <<= 1) {
        int v = __shfl_up(run, off);
        if (lane >= off) run += v;
    }
    if (lane == 63) wsum[w] = run;
    __syncthreads();
    int base = 0;
    for (int u = 0; u < w; ++u) base += wsum[u];
    base += run - tot;
#pragma unroll
    for (int j = 0; j < 4; ++j) {
        if (i0 + j < nn) {
            int node = node0 + i0 + j;
            offs[node] = ((uint)(e0p + base) << 10) | (uint)x[j];
            cur[i0 + j] = base;
            dinv[node] = rsqrtf((float)(x[j] + 1));
            for (int k = x[j]; k < px[j]; ++k) csr[e0p + base + k] = N;  // pad -> zero row
            base += px[j];
        }
    }
    __syncthreads();
    for (int e = e0 + t; e < e1; e += 256) {
        uint v = ebuf[e];
        int p = atomicAdd(&cur[v >> 22], 1);
        csr[e0p + p] = (int)(v & 0x3FFFFFu);
    }
}

// ================= MFMA GEMM (global_load_lds, m97 structure): out = bf16((A@Wt^T)*dinv) ===

template <int ABF16, int NT>
__global__ __launch_bounds__(256) void k_gemm_mfma(
    const void* __restrict__ Ap, const ushort* __restrict__ Wt,
    const float* __restrict__ dinv, ushort* __restrict__ outb, int N) {
    constexpr int K = NT * 64;
    constexpr int ASZ = ABF16 ? 128 * 64 * 2 : 128 * 64 * 4;
    __shared__ __align__(16) char asb[ASZ];
    __shared__ __align__(16) char bsb[128 * 64 * 2];
    const int tid = threadIdx.x;
    const int row0 = blockIdx.x * 128;
    const int w = tid >> 6, l = tid & 63;
    const int lr = l & 15, lk = l >> 4;
    f32x4 acc[2][8] = {};

    for (int t = 0; t < NT; ++t) {
        const int kb = t * 64;
        if constexpr (ABF16 == 0) {
            const char* A = (const char*)Ap;
#pragma unroll
            for (int i = 0; i < 8; ++i) {
                int b = (w << 13) + (i << 10) + (l << 4);
                int r = b >> 8, cb = b & 255;
                int sb = cb ^ ((r & 15) << 4);
                int gr = row0 + r;
                if (gr < N)
                    gl_lds16(A + ((size_t)gr * K + kb) * 4 + sb,
                             asb + (w << 13) + (i << 10));
            }
        } else {
            const char* A = (const char*)Ap;
#pragma unroll
            for (int i = 0; i < 4; ++i) {
                int b = (w << 12) + (i << 10) + (l << 4);
                int r = b >> 7, cb = b & 127;
                int sb = cb ^ ((r & 7) << 4);
                int gr = row0 + r;
                if (gr < N)
                    gl_lds16(A + ((size_t)gr * K + kb) * 2 + sb,
                             asb + (w << 12) + (i << 10));
            }
        }
#pragma unroll
        for (int i = 0; i < 4; ++i) {
            int b = (w << 12) + (i << 10) + (l << 4);
            int r = b >> 7, cb = b & 127;
            int sb = cb ^ ((r & 7) << 4);
            gl_lds16((const char*)Wt + ((size_t)r * K + kb) * 2 + sb,
                     bsb + (w << 12) + (i << 10));
        }
        __syncthreads();
        const int wr0 = w * 32;
#pragma unroll
        for (int ks = 0; ks < 2; ++ks) {
            short8 a0, a1;
            const int r0 = wr0 + lr, r1 = wr0 + 16 + lr;
            if constexpr (ABF16 == 0) {
                const int c0 = ks * 128 + lk * 32;
                float4 v00 = *(const float4*)(asb + (r0 << 8) + ((c0) ^ ((r0 & 15) << 4)));
                float4 v01 = *(const float4*)(asb + (r0 << 8) + ((c0 + 16) ^ ((r0 & 15) << 4)));
                float4 v10 = *(const float4*)(asb + (r1 << 8) + ((c0) ^ ((r1 & 15) << 4)));
                float4 v11 = *(const float4*)(asb + (r1 << 8) + ((c0 + 16) ^ ((r1 & 15) << 4)));
                a0[0] = (short)f2b(v00.x); a0[1] = (short)f2b(v00.y);
                a0[2] = (short)f2b(v00.z); a0[3] = (short)f2b(v00.w);
                a0[4] = (short)f2b(v01.x); a0[5] = (short)f2b(v01.y);
                a0[6] = (short)f2b(v01.z); a0[7] = (short)f2b(v01.w);
                a1[0] = (short)f2b(v10.x); a1[1] = (short)f2b(v10.y);
                a1[2] = (short)f2b(v10.z); a1[3] = (short)f2b(v10.w);
                a1[4] = (short)f2b(v11.x); a1[5] = (short)f2b(v11.y);
                a1[6] = (short)f2b(v11.z); a1[7] = (short)f2b(v11.w);
            } else {
                const int c0 = ks * 64 + lk * 16;
                a0 = *(const short8*)(asb + (r0 << 7) + (c0 ^ ((r0 & 7) << 4)));
                a1 = *(const short8*)(asb + (r1 << 7) + (c0 ^ ((r1 & 7) << 4)));
            }
            const int c0b = ks * 64 + lk * 16;
#pragma unroll
            for (int nf = 0; nf < 8; ++nf) {
                const int nr = nf * 16 + lr;
                short8 bf = *(const short8*)(bsb + (nr << 7) + (c0b ^ ((nr & 7) << 4)));
                acc[0][nf] = __builtin_amdgcn_mfma_f32_16x16x32_bf16(a0, bf, acc[0][nf], 0, 0, 0);
                acc[1][nf] = __builtin_amdgcn_mfma_f32_16x16x32_bf16(a1, bf, acc[1][nf], 0, 0, 0);
            }
        }
        __syncthreads();
    }
#pragma unroll
    for (int mf = 0; mf < 2; ++mf) {
#pragma unroll
        for (int r = 0; r < 4; ++r) {
            int row = row0 + w * 32 + mf * 16 + lk * 4 + r;
            if (row < N) {
                float dv = dinv[row];
#pragma unroll
                for (int nf = 0; nf < 8; ++nf)
                    outb[(size_t)row * 128 + nf * 16 + lr] = f2b(acc[mf][nf][r] * dv);
            }
        }
    }
}

// ================= SpMM: 4 rows per gather instruction (uint4/lane, 16 lanes/row) ==========
// hs4: bf16 rows as uint4[16] (256B). Row N is all-zero (padding target).
// offs packed: (padded_begin << 10) | deg. Quarter q handles edge 4*j+q.

__global__ __launch_bounds__(256) void k_spmm(
    const uint4* __restrict__ hs4, const int* __restrict__ csr,
    const uint* __restrict__ offs, const float* __restrict__ dinv,
    const float* __restrict__ bias, uint4* __restrict__ outb, int N) {
    int node = blockIdx.x * 4 + (threadIdx.x >> 6);
    if (node >= N) return;
    int l = threadIdx.x & 63;
    int q = l >> 4, ql = l & 15;
    uint pv = offs[node];
    int beg = (int)(pv >> 10), deg = (int)(pv & 1023u);
    int pend = beg + ((deg + 7) & ~7);
    float a[8] = {};
    if (q == 0) {   // self loop
        uint4 s = hs4[(size_t)node * 16 + ql];
        a[0] = blo(s.x); a[1] = bhi(s.x); a[2] = blo(s.y); a[3] = bhi(s.y);
        a[4] = blo(s.z); a[5] = bhi(s.z); a[6] = blo(s.w); a[7] = bhi(s.w);
    }
    int i = beg;
    for (; i + 32 <= pend; i += 32) {      // 8 gathers in flight, 32 edges
        uint4 v[8];
#pragma unroll
        for (int j = 0; j < 8; ++j) {
            int src = csr[i + 4 * j + q];
            v[j] = hs4[(size_t)src * 16 + ql];
        }
#pragma unroll
        for (int j = 0; j < 8; ++j) {
            a[0] += blo(v[j].x); a[1] += bhi(v[j].x);
            a[2] += blo(v[j].y); a[3] += bhi(v[j].y);
            a[4] += blo(v[j].z); a[5] += bhi(v[j].z);
            a[6] += blo(v[j].w); a[7] += bhi(v[j].w);
        }
    }
    if (i + 16 <= pend) {                  // 4 gathers, 16 edges
        uint4 v[4];
#pragma unroll
        for (int j = 0; j < 4; ++j) {
            int src = csr[i + 4 * j + q];
            v[j] = hs4[(size_t)src * 16 + ql];
        }
#pragma unroll
        for (int j = 0; j < 4; ++j) {
            a[0] += blo(v[j].x); a[1] += bhi(v[j].x);
            a[2] += blo(v[j].y); a[3] += bhi(v[j].y);
            a[4] += blo(v[j].z); a[5] += bhi(v[j].z);
            a[6] += blo(v[j].w); a[7] += bhi(v[j].w);
        }
        i += 16;
    }
    if (i < pend) {                        // 2 gathers, 8 edges
        uint4 v[2];
#pragma unroll
        for (int j = 0; j < 2; ++j) {
            int src = csr[i + 4 * j + q];
            v[j] = hs4[(size_t)src * 16 + ql];
        }
#pragma unroll
        for (int j = 0; j < 2; ++j) {
            a[0] += blo(v[j].x); a[1] += bhi(v[j].x);
            a[2] += blo(v[j].y); a[3] += bhi(v[j].y);
            a[4] += blo(v[j].z); a[5] += bhi(v[j].z);
            a[6] += blo(v[j].w); a[7] += bhi(v[j].w);
        }
    }
#pragma unroll
    for (int k = 0; k < 8; ++k) {
        a[k] += __shfl_xor(a[k], 16);
        a[k] += __shfl_xor(a[k], 32);
    }
    if (q == 0) {
        float dv = dinv[node];
        float4 b0 = ((const float4*)bias)[ql * 2];
        float4 b1 = ((const float4*)bias)[ql * 2 + 1];
        float o0 = fmaxf(fmaf(a[0], dv, b0.x), 0.f);
        float o1 = fmaxf(fmaf(a[1], dv, b0.y), 0.f);
        float o2 = fmaxf(fmaf(a[2], dv, b0.z), 0.f);
        float o3 = fmaxf(fmaf(a[3], dv, b0.w), 0.f);
        float o4 = fmaxf(fmaf(a[4], dv, b1.x), 0.f);
        float o5 = fmaxf(fmaf(a[5], dv, b1.y), 0.f);
        float o6 = fmaxf(fmaf(a[6], dv, b1.z), 0.f);
        float o7 = fmaxf(fmaf(a[7], dv, b1.w), 0.f);
        uint4 o;
        o.x = ((uint)f2b(o1) << 16) | (uint)f2b(o0);
        o.y = ((uint)f2b(o3) << 16) | (uint)f2b(o2);
        o.z = ((uint)f2b(o5) << 16) | (uint)f2b(o4);
        o.w = ((uint)f2b(o7) << 16) | (uint)f2b(o6);
        outb[(size_t)node * 16 + ql] = o;
    }
}

// ================= pooling =================

__global__ void k_pool(const uint* __restrict__ h, const int* __restrict__ gstart,
                       float* __restrict__ psum, int G) {
    int g = blockIdx.x >> 3, sl = blockIdx.x & 7;
    int r0 = gstart[g], r1 = gstart[g + 1];
    int t = threadIdx.x;
    float sx = 0.f, sy = 0.f;
    for (int r = r0 + sl; r < r1; r += 8) {
        uint u = h[(size_t)r * 64 + t];
        sx += blo(u); sy += bhi(u);
    }
    atomicAdd(&psum[g * 128 + 2 * t], sx);
    atomicAdd(&psum[g * 128 + 2 * t + 1], sy);
}

__global__ void k_div(const float* __restrict__ psum, const int* __restrict__ gstart,
                      float* __restrict__ out, int total) {
    int i = blockIdx.x * blockDim.x + threadIdx.x;
    if (i < total) {
        int g = i >> 7;
        float c = (float)(gstart[g + 1] - gstart[g]);
        out[i] = psum[i] / fmaxf(c, 1.f);
    }
}

// ================= launch =================

extern "C" void kernel_launch(void* const* d_in, const int* in_sizes, int n_in,
                              void* d_out, int out_size, void* d_ws, size_t ws_size,
                              hipStream_t stream) {
    const float* x     = (const float*)d_in[0];
    const int*   ei    = (const int*)d_in[1];
    const int*   batch = (const int*)d_in[2];
    const float* W1    = (const float*)d_in[3];
    const float* b1    = (const float*)d_in[4];
    const float* W2    = (const float*)d_in[5];
    const float* b2    = (const float*)d_in[6];
    float* outp = (float*)d_out;

    const int N = in_sizes[2];
    const int E = in_sizes[1] / 2;
    const int D = in_sizes[0] / N;   // 512
    const int H = in_sizes[4];       // 128
    const int G = out_size / H;      // 64
    const int NB = (N + 1023) >> 10; // <= 128

    char* ws = (char*)d_ws;
    size_t off = 0;
    auto alloc = [&](size_t bytes) -> char* {
        char* p = ws + off;
        off = (off + bytes + 255) & ~(size_t)255;
        return p;
    };
    float*  dinv    = (float*)alloc((size_t)N * 4);
    uint*   offs    = (uint*)alloc((size_t)N * 4);
    int*    gstart  = (int*)alloc((size_t)(G + 1) * 4);
    float*  psum    = (float*)alloc((size_t)G * H * 4);
    int*    bcur    = (int*)alloc(128 * 4);
    ushort* wt1b    = (ushort*)alloc((size_t)H * D * 2);
    ushort* wt2b    = (ushort*)alloc((size_t)H * H * 2);
    int*    csr     = (int*)alloc((size_t)NB * CCAP * 4);
    char*   hbase   = alloc(((size_t)N * 2 + 8) * H * 2);   // hb0 (+zero row) + hb1
    ushort* hb0     = (ushort*)hbase;
    ushort* hb1     = (ushort*)(hbase + ((size_t)N + 8) * H * 2);
    uint*   ebuf    = (uint*)hbase;                          // transient alias
    (void)ws_size; (void)n_in;

    int c1b = (128 * D + 255) / 256;
    int c2b = (128 * H + 255) / 256;
    int bb  = (N + 255) / 256;

    k_setup<<<c1b + c2b + bb + 1, 256, 0, stream>>>(
        W1, wt1b, D, W2, wt2b, H, batch, N, G, gstart, bcur, psum,
        (uint*)(hb0 + (size_t)N * H), c1b, c2b, bb);

    // CSR build (2 kernels)
    k_bucket_scatter<<<(E + 2047) / 2048, 256, 0, stream>>>(ei, E, NB, bcur, ebuf);
    k_bucket_sort<<<NB, 256, 0, stream>>>(ebuf, bcur, N, NB, offs, dinv, csr);

    int gblocks = (N + 127) / 128;
    // layer 1 (K = 512 -> NT = 8)
    k_gemm_mfma<0, 8><<<gblocks, 256, 0, stream>>>(x, wt1b, dinv, hb0, N);
    k_spmm<<<(N + 3) / 4, 256, 0, stream>>>((const uint4*)hb0, csr, offs, dinv, b1,
                                            (uint4*)hb1, N);
    // layer 2 (K = 128 -> NT = 2)
    k_gemm_mfma<1, 2><<<gblocks, 256, 0, stream>>>(hb1, wt2b, dinv, hb0, N);
    k_spmm<<<(N + 3) / 4, 256, 0, stream>>>((const uint4*)hb0, csr, offs, dinv, b2,
                                            (uint4*)hb1, N);
    // pool
    k_pool<<<G * 8, 64, 0, stream>>>((const uint*)hb1, gstart, psum, G);
    k_div<<<(G * H + 255) / 256, 256, 0, stream>>>(psum, gstart, outp, G * H);
}

// Round 9
// 313.711 us; speedup vs baseline: 1.3405x; 1.0328x over previous
//
#include <hip/hip_runtime.h>
#include <hip/hip_bf16.h>

typedef __attribute__((ext_vector_type(8))) short short8;
typedef __attribute__((ext_vector_type(4))) float f32x4;

__device__ __forceinline__ ushort f2b(float f) {
    union { float f; uint u; } v; v.f = f;
    uint u = v.u;
    u += 0x7fffu + ((u >> 16) & 1u);   // RNE
    return (ushort)(u >> 16);
}
__device__ __forceinline__ float blo(uint u) { return __uint_as_float(u << 16); }
__device__ __forceinline__ float bhi(uint u) { return __uint_as_float(u & 0xffff0000u); }

// async global->LDS, 16B per lane; LDS dest = wave-uniform base + lane*16
__device__ __forceinline__ void gl_lds16(const void* g, void* s) {
    __builtin_amdgcn_global_load_lds(
        (const __attribute__((address_space(1))) void*)g,
        (__attribute__((address_space(3))) void*)s, 16, 0, 0);
}

#define ECAP 32768   // ebuf slots per bucket (expected ~16.3K, huge headroom)
#define CCAP 40960   // csr slots per bucket (ECAP + 8K pad)

// ================= fused setup + bucket-scatter =================
// roles by blockIdx: [0,c1b) cvt W1 | [c1b,c1b+c2b) cvt W2 | bb blocks bounds |
// 1 block zeros (psum, dinv[N], hb0 zero row) | rest: edge scatter into ebuf.
// bcur must be zeroed by a prior memset.

__global__ __launch_bounds__(256) void k_setup_scatter(
    const float* __restrict__ W1, ushort* __restrict__ wt1b, int D,
    const float* __restrict__ W2, ushort* __restrict__ wt2b, int H,
    const int* __restrict__ batch, int N, int G, int* __restrict__ gstart,
    float* __restrict__ psum, float* __restrict__ dinv, uint* __restrict__ hb0zrow,
    const int* __restrict__ ei, int E, int NB, int* __restrict__ bcur,
    uint* __restrict__ ebuf, int c1b, int c2b, int bb) {
    __shared__ int h[128], gb[128], lc[128];
    int b = blockIdx.x, t = threadIdx.x;
    if (b < c1b) {
        int o = b * 256 + t;
        if (o < 128 * D) {
            int n = o / D, k = o - n * D;
            wt1b[o] = f2b(W1[(size_t)k * 128 + n]);
        }
    } else if (b < c1b + c2b) {
        int o = (b - c1b) * 256 + t;
        if (o < 128 * H) {
            int n = o / H, k = o - n * H;
            wt2b[o] = f2b(W2[(size_t)k * 128 + n]);
        }
    } else if (b < c1b + c2b + bb) {
        int i = (b - c1b - c2b) * 256 + t;
        if (i < N) {
            int bt = batch[i];
            int prev = (i == 0) ? -1 : batch[i - 1];
            for (int g = prev + 1; g <= bt; ++g) gstart[g] = i;
            if (i == N - 1)
                for (int g = bt + 1; g <= G; ++g) gstart[g] = N;
        }
    } else if (b == c1b + c2b + bb) {
        for (int i = t; i < G * H; i += 256) psum[i] = 0.f;
        if (t == 0) dinv[N] = 0.f;            // padding edges contribute 0
        for (int i = t; i < 64; i += 256) hb0zrow[i] = 0u;
    } else {
        // ---- scatter role ----
        int sb = b - (c1b + c2b + bb + 1);
        if (t < 128) { h[t] = 0; lc[t] = 0; }
        __syncthreads();
        int e0 = sb * 2048;
        int r[8], c[8], bk[8];
#pragma unroll
        for (int u = 0; u < 8; ++u) {
            int e = e0 + u * 256 + t;
            if (e < E) {
                r[u] = ei[e];
                c[u] = ei[E + e];
                bk[u] = c[u] >> 10;
                atomicAdd(&h[bk[u]], 1);
            }
        }
        __syncthreads();
        if (t < NB && h[t]) gb[t] = atomicAdd(&bcur[t], h[t]);
        __syncthreads();
#pragma unroll
        for (int u = 0; u < 8; ++u) {
            int e = e0 + u * 256 + t;
            if (e < E) {
                int p = gb[bk[u]] + atomicAdd(&lc[bk[u]], 1);
                ebuf[(size_t)bk[u] * ECAP + p] = ((uint)(c[u] & 1023) << 22) | (uint)r[u];
            }
        }
    }
}

// ================= bucket sort body (one block per bucket) =================
// LDS counting sort -> padded csr, packed offs, dinv. offs[node]=(begin<<10)|deg.

__device__ __forceinline__ void sort_body(const uint* __restrict__ ebuf,
                                          const int* __restrict__ bcur,
                                          int N, int b,
                                          uint* __restrict__ offs,
                                          float* __restrict__ dinv,
                                          int* __restrict__ csr, char* smem) {
    int* cnt = (int*)smem;
    int* cur = (int*)(smem + 4096);
    int* wsum = (int*)(smem + 8192);
    int t = threadIdx.x;
    int node0 = b << 10;
    int nn = min(1024, N - node0);
    for (int i = t; i < nn; i += 256) cnt[i] = 0;
    __syncthreads();
    int e0 = b * ECAP, e1 = e0 + bcur[b];
    int e0p = b * CCAP;
    for (int e = e0 + t; e < e1; e += 256) atomicAdd(&cnt[ebuf[e] >> 22], 1);
    __syncthreads();
    int i0 = t * 4;
    int x[4], px[4];
#pragma unroll
    for (int j = 0; j < 4; ++j) {
        x[j] = (i0 + j < nn) ? cnt[i0 + j] : 0;
        px[j] = (x[j] + 7) & ~7;
    }
    int tot = px[0] + px[1] + px[2] + px[3];
    int run = tot;
    int lane = t & 63, w = t >> 6;
#pragma unroll
    for (int off = 1; off < 64; off <<= 1) {
        int v = __shfl_up(run, off);
        if (lane >= off) run += v;
    }
    if (lane == 63) wsum[w] = run;
    __syncthreads();
    int base = 0;
    for (int u = 0; u < w; ++u) base += wsum[u];
    base += run - tot;
#pragma unroll
    for (int j = 0; j < 4; ++j) {
        if (i0 + j < nn) {
            int node = node0 + i0 + j;
            offs[node] = ((uint)(e0p + base) << 10) | (uint)x[j];
            cur[i0 + j] = base;
            dinv[node] = rsqrtf((float)(x[j] + 1));
            for (int k = x[j]; k < px[j]; ++k) csr[e0p + base + k] = N;  // pad
            base += px[j];
        }
    }
    __syncthreads();
    for (int e = e0 + t; e < e1; e += 256) {
        uint v = ebuf[e];
        int p = atomicAdd(&cur[v >> 22], 1);
        csr[e0p + p] = (int)(v & 0x3FFFFFu);
    }
}

// ================= MFMA GEMM body (global_load_lds, m97 structure) =================
// out = bf16((A@Wt^T) [* dinv]);  A fp32 (ABF16=0, cvt at frag read) or bf16.

template <int ABF16, int NT, bool SCALE>
__device__ __forceinline__ void gemm_body(
    const void* __restrict__ Ap, const ushort* __restrict__ Wt,
    const float* __restrict__ dinv, ushort* __restrict__ outb, int N, int bid,
    char* smem) {
    constexpr int K = NT * 64;
    char* asb = smem;
    char* bsb = smem + (ABF16 ? 128 * 64 * 2 : 128 * 64 * 4);
    const int tid = threadIdx.x;
    const int row0 = bid * 128;
    const int w = tid >> 6, l = tid & 63;
    const int lr = l & 15, lk = l >> 4;
    f32x4 acc[2][8] = {};

    for (int t = 0; t < NT; ++t) {
        const int kb = t * 64;
        if constexpr (ABF16 == 0) {
            const char* A = (const char*)Ap;
#pragma unroll
            for (int i = 0; i < 8; ++i) {
                int b = (w << 13) + (i << 10) + (l << 4);
                int r = b >> 8, cb = b & 255;
                int sb = cb ^ ((r & 15) << 4);
                int gr = row0 + r;
                if (gr < N)
                    gl_lds16(A + ((size_t)gr * K + kb) * 4 + sb,
                             asb + (w << 13) + (i << 10));
            }
        } else {
            const char* A = (const char*)Ap;
#pragma unroll
            for (int i = 0; i < 4; ++i) {
                int b = (w << 12) + (i << 10) + (l << 4);
                int r = b >> 7, cb = b & 127;
                int sb = cb ^ ((r & 7) << 4);
                int gr = row0 + r;
                if (gr < N)
                    gl_lds16(A + ((size_t)gr * K + kb) * 2 + sb,
                             asb + (w << 12) + (i << 10));
            }
        }
#pragma unroll
        for (int i = 0; i < 4; ++i) {
            int b = (w << 12) + (i << 10) + (l << 4);
            int r = b >> 7, cb = b & 127;
            int sb = cb ^ ((r & 7) << 4);
            gl_lds16((const char*)Wt + ((size_t)r * K + kb) * 2 + sb,
                     bsb + (w << 12) + (i << 10));
        }
        __syncthreads();
        const int wr0 = w * 32;
#pragma unroll
        for (int ks = 0; ks < 2; ++ks) {
            short8 a0, a1;
            const int r0 = wr0 + lr, r1 = wr0 + 16 + lr;
            if constexpr (ABF16 == 0) {
                const int c0 = ks * 128 + lk * 32;
                float4 v00 = *(const float4*)(asb + (r0 << 8) + ((c0) ^ ((r0 & 15) << 4)));
                float4 v01 = *(const float4*)(asb + (r0 << 8) + ((c0 + 16) ^ ((r0 & 15) << 4)));
                float4 v10 = *(const float4*)(asb + (r1 << 8) + ((c0) ^ ((r1 & 15) << 4)));
                float4 v11 = *(const float4*)(asb + (r1 << 8) + ((c0 + 16) ^ ((r1 & 15) << 4)));
                a0[0] = (short)f2b(v00.x); a0[1] = (short)f2b(v00.y);
                a0[2] = (short)f2b(v00.z); a0[3] = (short)f2b(v00.w);
                a0[4] = (short)f2b(v01.x); a0[5] = (short)f2b(v01.y);
                a0[6] = (short)f2b(v01.z); a0[7] = (short)f2b(v01.w);
                a1[0] = (short)f2b(v10.x); a1[1] = (short)f2b(v10.y);
                a1[2] = (short)f2b(v10.z); a1[3] = (short)f2b(v10.w);
                a1[4] = (short)f2b(v11.x); a1[5] = (short)f2b(v11.y);
                a1[6] = (short)f2b(v11.z); a1[7] = (short)f2b(v11.w);
            } else {
                const int c0 = ks * 64 + lk * 16;
                a0 = *(const short8*)(asb + (r0 << 7) + (c0 ^ ((r0 & 7) << 4)));
                a1 = *(const short8*)(asb + (r1 << 7) + (c0 ^ ((r1 & 7) << 4)));
            }
            const int c0b = ks * 64 + lk * 16;
#pragma unroll
            for (int nf = 0; nf < 8; ++nf) {
                const int nr = nf * 16 + lr;
                short8 bf = *(const short8*)(bsb + (nr << 7) + (c0b ^ ((nr & 7) << 4)));
                acc[0][nf] = __builtin_amdgcn_mfma_f32_16x16x32_bf16(a0, bf, acc[0][nf], 0, 0, 0);
                acc[1][nf] = __builtin_amdgcn_mfma_f32_16x16x32_bf16(a1, bf, acc[1][nf], 0, 0, 0);
            }
        }
        __syncthreads();
    }
#pragma unroll
    for (int mf = 0; mf < 2; ++mf) {
#pragma unroll
        for (int r = 0; r < 4; ++r) {
            int row = row0 + w * 32 + mf * 16 + lk * 4 + r;
            if (row < N) {
                float dv = 1.f;
                if constexpr (SCALE) dv = dinv[row];
#pragma unroll
                for (int nf = 0; nf < 8; ++nf)
                    outb[(size_t)row * 128 + nf * 16 + lr] = f2b(acc[mf][nf][r] * dv);
            }
        }
    }
}

// standalone GEMM (layer 2, bf16 A, dinv in epilogue)
template <int ABF16, int NT, bool SCALE>
__global__ __launch_bounds__(256) void k_gemm(
    const void* __restrict__ Ap, const ushort* __restrict__ Wt,
    const float* __restrict__ dinv, ushort* __restrict__ outb, int N) {
    constexpr int S = (ABF16 ? 128 * 64 * 2 : 128 * 64 * 4) + 128 * 64 * 2;
    __shared__ __align__(16) char smem[S];
    gemm_body<ABF16, NT, SCALE>(Ap, Wt, dinv, outb, N, blockIdx.x, smem);
}

// fused GEMM1 (no dinv) + bucket sort: blocks [0,gblocks) GEMM, rest sort
template <int ABF16, int NT>
__global__ __launch_bounds__(256) void k_gemm_sort(
    const void* __restrict__ Ap, const ushort* __restrict__ Wt,
    ushort* __restrict__ outb, int N, int gblocks,
    const uint* __restrict__ ebuf, const int* __restrict__ bcur,
    uint* __restrict__ offs, float* __restrict__ dinv, int* __restrict__ csr) {
    __shared__ __align__(16) char smem[128 * 64 * 4 + 128 * 64 * 2];
    if ((int)blockIdx.x < gblocks)
        gemm_body<ABF16, NT, false>(Ap, Wt, nullptr, outb, N, blockIdx.x, smem);
    else
        sort_body(ebuf, bcur, N, blockIdx.x - gblocks, offs, dinv, csr, smem);
}

// ================= SpMM: 4 rows/gather (uint4/lane, 16 lanes/row) ==========
// EDINV: multiply each gathered row by dinv[src] (layer 1, unscaled hs).
// POOL: accumulate relu'd row into per-graph pooled sums instead of storing.

template <int EDINV, int POOL>
__global__ __launch_bounds__(256) void k_spmm(
    const uint4* __restrict__ hs4, const int* __restrict__ csr,
    const uint* __restrict__ offs, const float* __restrict__ dinv,
    const float* __restrict__ bias, uint4* __restrict__ outb,
    float* __restrict__ psum, const int* __restrict__ batch, int N) {
    __shared__ float pacc[POOL ? 4 : 1][128];
    __shared__ int gid[4];
    int wv = threadIdx.x >> 6;
    int node = blockIdx.x * 4 + wv;
    int l = threadIdx.x & 63;
    int q = l >> 4, ql = l & 15;
    bool active = node < N;
    if constexpr (!POOL) { if (!active) return; }
    if constexpr (POOL) {
        for (int i = threadIdx.x; i < 512; i += 256) ((float*)pacc)[i] = 0.f;
        if (l == 0) gid[wv] = active ? batch[node] : -1;
        __syncthreads();
    }
    float a[8] = {};
    float dvn = 0.f;
    int beg = 0, pend = 0;
    if (active) {
        uint pv = offs[node];
        beg = (int)(pv >> 10);
        pend = beg + (((int)(pv & 1023u) + 7) & ~7);
        dvn = dinv[node];
        if (q == 0) {   // self loop
            uint4 s = hs4[(size_t)node * 16 + ql];
            float sc = EDINV ? dvn : 1.f;
            a[0] = blo(s.x) * sc; a[1] = bhi(s.x) * sc;
            a[2] = blo(s.y) * sc; a[3] = bhi(s.y) * sc;
            a[4] = blo(s.z) * sc; a[5] = bhi(s.z) * sc;
            a[6] = blo(s.w) * sc; a[7] = bhi(s.w) * sc;
        }
    }
    int i = beg;
    for (; i + 32 <= pend; i += 32) {      // 8 gathers in flight, 32 edges
        int src[8];
#pragma unroll
        for (int j = 0; j < 8; ++j) src[j] = csr[i + 4 * j + q];
        float dv[8];
#pragma unroll
        for (int j = 0; j < 8; ++j) dv[j] = EDINV ? dinv[src[j]] : 1.f;
        uint4 v[8];
#pragma unroll
        for (int j = 0; j < 8; ++j) v[j] = hs4[(size_t)src[j] * 16 + ql];
#pragma unroll
        for (int j = 0; j < 8; ++j) {
            a[0] = fmaf(blo(v[j].x), dv[j], a[0]); a[1] = fmaf(bhi(v[j].x), dv[j], a[1]);
            a[2] = fmaf(blo(v[j].y), dv[j], a[2]); a[3] = fmaf(bhi(v[j].y), dv[j], a[3]);
            a[4] = fmaf(blo(v[j].z), dv[j], a[4]); a[5] = fmaf(bhi(v[j].z), dv[j], a[5]);
            a[6] = fmaf(blo(v[j].w), dv[j], a[6]); a[7] = fmaf(bhi(v[j].w), dv[j], a[7]);
        }
    }
    if (i + 16 <= pend) {                  // 4 gathers, 16 edges
        int src[4];
#pragma unroll
        for (int j = 0; j < 4; ++j) src[j] = csr[i + 4 * j + q];
        float dv[4];
#pragma unroll
        for (int j = 0; j < 4; ++j) dv[j] = EDINV ? dinv[src[j]] : 1.f;
        uint4 v[4];
#pragma unroll
        for (int j = 0; j < 4; ++j) v[j] = hs4[(size_t)src[j] * 16 + ql];
#pragma unroll
        for (int j = 0; j < 4; ++j) {
            a[0] = fmaf(blo(v[j].x), dv[j], a[0]); a[1] = fmaf(bhi(v[j].x), dv[j], a[1]);
            a[2] = fmaf(blo(v[j].y), dv[j], a[2]); a[3] = fmaf(bhi(v[j].y), dv[j], a[3]);
            a[4] = fmaf(blo(v[j].z), dv[j], a[4]); a[5] = fmaf(bhi(v[j].z), dv[j], a[5]);
            a[6] = fmaf(blo(v[j].w), dv[j], a[6]); a[7] = fmaf(bhi(v[j].w), dv[j], a[7]);
        }
        i += 16;
    }
    if (i < pend) {                        // 2 gathers, 8 edges
        int src[2];
#pragma unroll
        for (int j = 0; j < 2; ++j) src[j] = csr[i + 4 * j + q];
        float dv[2];
#pragma unroll
        for (int j = 0; j < 2; ++j) dv[j] = EDINV ? dinv[src[j]] : 1.f;
        uint4 v[2];
#pragma unroll
        for (int j = 0; j < 2; ++j) v[j] = hs4[(size_t)src[j] * 16 + ql];
#pragma unroll
        for (int j = 0; j < 2; ++j) {
            a[0] = fmaf(blo(v[j].x), dv[j], a[0]); a[1] = fmaf(bhi(v[j].x), dv[j], a[1]);
            a[2] = fmaf(blo(v[j].y), dv[j], a[2]); a[3] = fmaf(bhi(v[j].y), dv[j], a[3]);
            a[4] = fmaf(blo(v[j].z), dv[j], a[4]); a[5] = fmaf(bhi(v[j].z), dv[j], a[5]);
            a[6] = fmaf(blo(v[j].w), dv[j], a[6]); a[7] = fmaf(bhi(v[j].w), dv[j], a[7]);
        }
    }
#pragma unroll
    for (int k = 0; k < 8; ++k) {
        a[k] += __shfl_xor(a[k], 16);
        a[k] += __shfl_xor(a[k], 32);
    }
    float o[8];
    if (active && q == 0) {
        float4 b0 = ((const float4*)bias)[ql * 2];
        float4 b1 = ((const float4*)bias)[ql * 2 + 1];
        o[0] = fmaxf(fmaf(a[0], dvn, b0.x), 0.f);
        o[1] = fmaxf(fmaf(a[1], dvn, b0.y), 0.f);
        o[2] = fmaxf(fmaf(a[2], dvn, b0.z), 0.f);
        o[3] = fmaxf(fmaf(a[3], dvn, b0.w), 0.f);
        o[4] = fmaxf(fmaf(a[4], dvn, b1.x), 0.f);
        o[5] = fmaxf(fmaf(a[5], dvn, b1.y), 0.f);
        o[6] = fmaxf(fmaf(a[6], dvn, b1.z), 0.f);
        o[7] = fmaxf(fmaf(a[7], dvn, b1.w), 0.f);
    }
    if constexpr (POOL) {
        if (active && q == 0) {
#pragma unroll
            for (int k = 0; k < 8; ++k) pacc[wv][ql * 8 + k] = o[k];
        }
        __syncthreads();
        int t = threadIdx.x;
        if (t < 128) {
            float run = 0.f; int prev = -1;
#pragma unroll
            for (int w2 = 0; w2 < 4; ++w2) {
                int g = gid[w2];
                if (g < 0) continue;
                if (g != prev && prev >= 0) { atomicAdd(&psum[prev * 128 + t], run); run = 0.f; }
                run += pacc[w2][t];
                prev = g;
            }
            if (prev >= 0) atomicAdd(&psum[prev * 128 + t], run);
        }
    } else {
        if (q == 0) {
            uint4 ov;
            ov.x = ((uint)f2b(o[1]) << 16) | (uint)f2b(o[0]);
            ov.y = ((uint)f2b(o[3]) << 16) | (uint)f2b(o[2]);
            ov.z = ((uint)f2b(o[5]) << 16) | (uint)f2b(o[4]);
            ov.w = ((uint)f2b(o[7]) << 16) | (uint)f2b(o[6]);
            outb[(size_t)node * 16 + ql] = ov;
        }
    }
}

// ================= final divide =================

__global__ void k_div(const float* __restrict__ psum, const int* __restrict__ gstart,
                      float* __restrict__ out, int total) {
    int i = blockIdx.x * blockDim.x + threadIdx.x;
    if (i < total) {
        int g = i >> 7;
        float c = (float)(gstart[g + 1] - gstart[g]);
        out[i] = psum[i] / fmaxf(c, 1.f);
    }
}

// ================= launch =================

extern "C" void kernel_launch(void* const* d_in, const int* in_sizes, int n_in,
                              void* d_out, int out_size, void* d_ws, size_t ws_size,
                              hipStream_t stream) {
    const float* x     = (const float*)d_in[0];
    const int*   ei    = (const int*)d_in[1];
    const int*   batch = (const int*)d_in[2];
    const float* W1    = (const float*)d_in[3];
    const float* b1    = (const float*)d_in[4];
    const float* W2    = (const float*)d_in[5];
    const float* b2    = (const float*)d_in[6];
    float* outp = (float*)d_out;

    const int N = in_sizes[2];
    const int E = in_sizes[1] / 2;
    const int D = in_sizes[0] / N;   // 512
    const int H = in_sizes[4];       // 128
    const int G = out_size / H;      // 64
    const int NB = (N + 1023) >> 10; // <= 128

    char* ws = (char*)d_ws;
    size_t off = 0;
    auto alloc = [&](size_t bytes) -> char* {
        char* p = ws + off;
        off = (off + bytes + 255) & ~(size_t)255;
        return p;
    };
    float*  dinv    = (float*)alloc((size_t)(N + 1) * 4);
    uint*   offs    = (uint*)alloc((size_t)N * 4);
    int*    gstart  = (int*)alloc((size_t)(G + 1) * 4);
    float*  psum    = (float*)alloc((size_t)G * H * 4);
    int*    bcur    = (int*)alloc(128 * 4);
    ushort* wt1b    = (ushort*)alloc((size_t)H * D * 2);
    ushort* wt2b    = (ushort*)alloc((size_t)H * H * 2);
    int*    csr     = (int*)alloc((size_t)NB * CCAP * 4);
    uint*   ebuf    = (uint*)alloc((size_t)NB * ECAP * 4);   // own region now
    char*   hbase   = alloc(((size_t)N * 2 + 8) * H * 2);
    ushort* hb0     = (ushort*)hbase;                        // N+zero-row rows
    ushort* hb1     = (ushort*)(hbase + ((size_t)N + 8) * H * 2);
    (void)ws_size; (void)n_in;

    hipMemsetAsync(bcur, 0, 128 * 4, stream);

    int c1b = (128 * D + 255) / 256;
    int c2b = (128 * H + 255) / 256;
    int bb  = (N + 255) / 256;
    int scb = (E + 2047) / 2048;

    k_setup_scatter<<<c1b + c2b + bb + 1 + scb, 256, 0, stream>>>(
        W1, wt1b, D, W2, wt2b, H, batch, N, G, gstart, psum, dinv,
        (uint*)(hb0 + (size_t)N * H), ei, E, NB, bcur, ebuf, c1b, c2b, bb);

    int gblocks = (N + 127) / 128;
    // layer 1 GEMM (K=512, fp32 A, no dinv) fused with bucket sort
    k_gemm_sort<0, 8><<<gblocks + NB, 256, 0, stream>>>(
        x, wt1b, hb0, N, gblocks, ebuf, bcur, offs, dinv, csr);
    // layer 1 propagate (per-edge dinv[src])
    k_spmm<1, 0><<<(N + 3) / 4, 256, 0, stream>>>(
        (const uint4*)hb0, csr, offs, dinv, b1, (uint4*)hb1, nullptr, nullptr, N);
    // layer 2 GEMM (K=128, bf16 A, dinv in epilogue)
    k_gemm<1, 2, true><<<gblocks, 256, 0, stream>>>(hb1, wt2b, dinv, hb0, N);
    // layer 2 propagate fused with mean-pool accumulation
    k_spmm<0, 1><<<(N + 3) / 4, 256, 0, stream>>>(
        (const uint4*)hb0, csr, offs, dinv, b2, nullptr, psum, batch, N);
    // finalize mean
    k_div<<<(G * H + 255) / 256, 256, 0, stream>>>(psum, gstart, outp, G * H);
}

// Round 10
// 261.079 us; speedup vs baseline: 1.6108x; 1.2016x over previous
//
#include <hip/hip_runtime.h>
#include <hip/hip_bf16.h>

typedef __attribute__((ext_vector_type(8))) short short8;
typedef __attribute__((ext_vector_type(4))) float f32x4;

__device__ __forceinline__ ushort f2b(float f) {
    union { float f; uint u; } v; v.f = f;
    uint u = v.u;
    u += 0x7fffu + ((u >> 16) & 1u);   // RNE
    return (ushort)(u >> 16);
}
__device__ __forceinline__ float blo(uint u) { return __uint_as_float(u << 16); }
__device__ __forceinline__ float bhi(uint u) { return __uint_as_float(u & 0xffff0000u); }

// async global->LDS, 16B per lane; LDS dest = wave-uniform base + lane*16
__device__ __forceinline__ void gl_lds16(const void* g, void* s) {
    __builtin_amdgcn_global_load_lds(
        (const __attribute__((address_space(1))) void*)g,
        (__attribute__((address_space(3))) void*)s, 16, 0, 0);
}

#define ECAP 32768   // ebuf slots per bucket (expected ~16.3K)
#define CCAP 40960   // csr slots per bucket (ECAP + 8K pad)

// ================= fused setup + bucket-scatter =================

__global__ __launch_bounds__(256) void k_setup_scatter(
    const float* __restrict__ W1, ushort* __restrict__ wt1b, int D,
    const float* __restrict__ W2, ushort* __restrict__ wt2b, int H,
    const int* __restrict__ batch, int N, int G, int* __restrict__ gstart,
    float* __restrict__ psum, float* __restrict__ dinv, uint* __restrict__ hb0zrow,
    const int* __restrict__ ei, int E, int NB, int* __restrict__ bcur,
    uint* __restrict__ ebuf, int c1b, int c2b, int bb) {
    __shared__ int h[128], gb[128], lc[128];
    int b = blockIdx.x, t = threadIdx.x;
    if (b < c1b) {
        int o = b * 256 + t;
        if (o < 128 * D) {
            int n = o / D, k = o - n * D;
            wt1b[o] = f2b(W1[(size_t)k * 128 + n]);
        }
    } else if (b < c1b + c2b) {
        int o = (b - c1b) * 256 + t;
        if (o < 128 * H) {
            int n = o / H, k = o - n * H;
            wt2b[o] = f2b(W2[(size_t)k * 128 + n]);
        }
    } else if (b < c1b + c2b + bb) {
        int i = (b - c1b - c2b) * 256 + t;
        if (i < N) {
            int bt = batch[i];
            int prev = (i == 0) ? -1 : batch[i - 1];
            for (int g = prev + 1; g <= bt; ++g) gstart[g] = i;
            if (i == N - 1)
                for (int g = bt + 1; g <= G; ++g) gstart[g] = N;
        }
    } else if (b == c1b + c2b + bb) {
        for (int i = t; i < G * H; i += 256) psum[i] = 0.f;
        if (t == 0) dinv[N] = 0.f;
        for (int i = t; i < 64; i += 256) hb0zrow[i] = 0u;   // padding target row
    } else {
        // ---- scatter role ----
        int sb = b - (c1b + c2b + bb + 1);
        if (t < 128) { h[t] = 0; lc[t] = 0; }
        __syncthreads();
        int e0 = sb * 2048;
        int r[8], c[8], bk[8];
#pragma unroll
        for (int u = 0; u < 8; ++u) {
            int e = e0 + u * 256 + t;
            if (e < E) {
                r[u] = ei[e];
                c[u] = ei[E + e];
                bk[u] = c[u] >> 10;
                atomicAdd(&h[bk[u]], 1);
            }
        }
        __syncthreads();
        if (t < NB && h[t]) gb[t] = atomicAdd(&bcur[t], h[t]);
        __syncthreads();
#pragma unroll
        for (int u = 0; u < 8; ++u) {
            int e = e0 + u * 256 + t;
            if (e < E) {
                int p = gb[bk[u]] + atomicAdd(&lc[bk[u]], 1);
                ebuf[(size_t)bk[u] * ECAP + p] = ((uint)(c[u] & 1023) << 22) | (uint)r[u];
            }
        }
    }
}

// ================= bucket sort (standalone): LDS counting sort -> padded csr =================
// offs[node] = (padded_begin << 10) | deg;  padding entries -> row N (zero).

__global__ __launch_bounds__(256) void k_bucket_sort(const uint* __restrict__ ebuf,
                                                     const int* __restrict__ bcur,
                                                     int N, int NB,
                                                     uint* __restrict__ offs,
                                                     float* __restrict__ dinv,
                                                     int* __restrict__ csr) {
    __shared__ int cnt[1024];
    __shared__ int cur[1024];
    __shared__ int wsum[4];
    int t = threadIdx.x;
    int b = blockIdx.x;
    int node0 = b << 10;
    int nn = min(1024, N - node0);
    for (int i = t; i < nn; i += 256) cnt[i] = 0;
    __syncthreads();
    int e0 = b * ECAP, e1 = e0 + bcur[b];
    int e0p = b * CCAP;
    for (int e = e0 + t; e < e1; e += 256) atomicAdd(&cnt[ebuf[e] >> 22], 1);
    __syncthreads();
    int i0 = t * 4;
    int x[4], px[4];
#pragma unroll
    for (int j = 0; j < 4; ++j) {
        x[j] = (i0 + j < nn) ? cnt[i0 + j] : 0;
        px[j] = (x[j] + 7) & ~7;
    }
    int tot = px[0] + px[1] + px[2] + px[3];
    int run = tot;
    int lane = t & 63, w = t >> 6;
#pragma unroll
    for (int off = 1; off < 64; off <<= 1) {
        int v = __shfl_up(run, off);
        if (lane >= off) run += v;
    }
    if (lane == 63) wsum[w] = run;
    __syncthreads();
    int base = 0;
    for (int u = 0; u < w; ++u) base += wsum[u];
    base += run - tot;
#pragma unroll
    for (int j = 0; j < 4; ++j) {
        if (i0 + j < nn) {
            int node = node0 + i0 + j;
            offs[node] = ((uint)(e0p + base) << 10) | (uint)x[j];
            cur[i0 + j] = base;
            dinv[node] = rsqrtf((float)(x[j] + 1));
            for (int k = x[j]; k < px[j]; ++k) csr[e0p + base + k] = N;  // pad
            base += px[j];
        }
    }
    __syncthreads();
    for (int e = e0 + t; e < e1; e += 256) {
        uint v = ebuf[e];
        int p = atomicAdd(&cur[v >> 22], 1);
        csr[e0p + p] = (int)(v & 0x3FFFFFu);
    }
}

// ================= MFMA GEMM (global_load_lds): out = bf16((A@Wt^T) * dinv) =================

template <int ABF16, int NT, bool SCALE>
__global__ __launch_bounds__(256) void k_gemm(
    const void* __restrict__ Ap, const ushort* __restrict__ Wt,
    const float* __restrict__ dinv, ushort* __restrict__ outb, int N) {
    constexpr int K = NT * 64;
    constexpr int ASZ = ABF16 ? 128 * 64 * 2 : 128 * 64 * 4;
    __shared__ __align__(16) char asb[ASZ];
    __shared__ __align__(16) char bsb[128 * 64 * 2];
    const int tid = threadIdx.x;
    const int row0 = blockIdx.x * 128;
    const int w = tid >> 6, l = tid & 63;
    const int lr = l & 15, lk = l >> 4;
    f32x4 acc[2][8] = {};

    for (int t = 0; t < NT; ++t) {
        const int kb = t * 64;
        if constexpr (ABF16 == 0) {
            const char* A = (const char*)Ap;
#pragma unroll
            for (int i = 0; i < 8; ++i) {
                int b = (w << 13) + (i << 10) + (l << 4);
                int r = b >> 8, cb = b & 255;
                int sb = cb ^ ((r & 15) << 4);
                int gr = row0 + r;
                if (gr < N)
                    gl_lds16(A + ((size_t)gr * K + kb) * 4 + sb,
                             asb + (w << 13) + (i << 10));
            }
        } else {
            const char* A = (const char*)Ap;
#pragma unroll
            for (int i = 0; i < 4; ++i) {
                int b = (w << 12) + (i << 10) + (l << 4);
                int r = b >> 7, cb = b & 127;
                int sb = cb ^ ((r & 7) << 4);
                int gr = row0 + r;
                if (gr < N)
                    gl_lds16(A + ((size_t)gr * K + kb) * 2 + sb,
                             asb + (w << 12) + (i << 10));
            }
        }
#pragma unroll
        for (int i = 0; i < 4; ++i) {
            int b = (w << 12) + (i << 10) + (l << 4);
            int r = b >> 7, cb = b & 127;
            int sb = cb ^ ((r & 7) << 4);
            gl_lds16((const char*)Wt + ((size_t)r * K + kb) * 2 + sb,
                     bsb + (w << 12) + (i << 10));
        }
        __syncthreads();
        const int wr0 = w * 32;
#pragma unroll
        for (int ks = 0; ks < 2; ++ks) {
            short8 a0, a1;
            const int r0 = wr0 + lr, r1 = wr0 + 16 + lr;
            if constexpr (ABF16 == 0) {
                const int c0 = ks * 128 + lk * 32;
                float4 v00 = *(const float4*)(asb + (r0 << 8) + ((c0) ^ ((r0 & 15) << 4)));
                float4 v01 = *(const float4*)(asb + (r0 << 8) + ((c0 + 16) ^ ((r0 & 15) << 4)));
                float4 v10 = *(const float4*)(asb + (r1 << 8) + ((c0) ^ ((r1 & 15) << 4)));
                float4 v11 = *(const float4*)(asb + (r1 << 8) + ((c0 + 16) ^ ((r1 & 15) << 4)));
                a0[0] = (short)f2b(v00.x); a0[1] = (short)f2b(v00.y);
                a0[2] = (short)f2b(v00.z); a0[3] = (short)f2b(v00.w);
                a0[4] = (short)f2b(v01.x); a0[5] = (short)f2b(v01.y);
                a0[6] = (short)f2b(v01.z); a0[7] = (short)f2b(v01.w);
                a1[0] = (short)f2b(v10.x); a1[1] = (short)f2b(v10.y);
                a1[2] = (short)f2b(v10.z); a1[3] = (short)f2b(v10.w);
                a1[4] = (short)f2b(v11.x); a1[5] = (short)f2b(v11.y);
                a1[6] = (short)f2b(v11.z); a1[7] = (short)f2b(v11.w);
            } else {
                const int c0 = ks * 64 + lk * 16;
                a0 = *(const short8*)(asb + (r0 << 7) + (c0 ^ ((r0 & 7) << 4)));
                a1 = *(const short8*)(asb + (r1 << 7) + (c0 ^ ((r1 & 7) << 4)));
            }
            const int c0b = ks * 64 + lk * 16;
#pragma unroll
            for (int nf = 0; nf < 8; ++nf) {
                const int nr = nf * 16 + lr;
                short8 bf = *(const short8*)(bsb + (nr << 7) + (c0b ^ ((nr & 7) << 4)));
                acc[0][nf] = __builtin_amdgcn_mfma_f32_16x16x32_bf16(a0, bf, acc[0][nf], 0, 0, 0);
                acc[1][nf] = __builtin_amdgcn_mfma_f32_16x16x32_bf16(a1, bf, acc[1][nf], 0, 0, 0);
            }
        }
        __syncthreads();
    }
#pragma unroll
    for (int mf = 0; mf < 2; ++mf) {
#pragma unroll
        for (int r = 0; r < 4; ++r) {
            int row = row0 + w * 32 + mf * 16 + lk * 4 + r;
            if (row < N) {
                float dv = 1.f;
                if constexpr (SCALE) dv = dinv[row];
#pragma unroll
                for (int nf = 0; nf < 8; ++nf)
                    outb[(size_t)row * 128 + nf * 16 + lr] = f2b(acc[mf][nf][r] * dv);
            }
        }
    }
}

// ================= SpMM: ONE NODE PER 16-LANE GROUP =================
// hs4 rows = uint4[16] (256B); row N zeroed (padding target). Padded deg -> multiples
// of 8, so edge bursts are exact: 16-deep (typical node, one burst) or 8-deep tail.
// No cross-lane reduction. 16 nodes per 256-thread block.

#define ACC8(v) { a[0] += blo(v.x); a[1] += bhi(v.x); a[2] += blo(v.y); a[3] += bhi(v.y); \
                  a[4] += blo(v.z); a[5] += bhi(v.z); a[6] += blo(v.w); a[7] += bhi(v.w); }

template <int POOL>
__global__ __launch_bounds__(256) void k_spmm(
    const uint4* __restrict__ hs4, const int* __restrict__ csr,
    const uint* __restrict__ offs, const float* __restrict__ dinv,
    const float* __restrict__ bias, uint4* __restrict__ outb,
    float* __restrict__ psum, const int* __restrict__ batch, int N) {
    __shared__ float4 pacc[POOL ? 16 : 1][32];
    __shared__ int gid[POOL ? 16 : 1];
    const int grp = threadIdx.x >> 4, ql = threadIdx.x & 15;
    const int node = blockIdx.x * 16 + grp;
    const bool active = node < N;
    float a[8] = {};
    int beg = 0, pend = 0;
    if (active) {
        uint pv = offs[node];
        beg = (int)(pv >> 10);
        pend = beg + (((int)(pv & 1023u) + 7) & ~7);
        uint4 s = hs4[(size_t)node * 16 + ql];   // self loop
        ACC8(s)
    }
    int i = beg;
    for (; i + 16 <= pend; i += 16) {            // 16 gathers in flight
        int4 s0 = *(const int4*)(csr + i);
        int4 s1 = *(const int4*)(csr + i + 4);
        int4 s2 = *(const int4*)(csr + i + 8);
        int4 s3 = *(const int4*)(csr + i + 12);
        uint4 v0 = hs4[(size_t)s0.x * 16 + ql];
        uint4 v1 = hs4[(size_t)s0.y * 16 + ql];
        uint4 v2 = hs4[(size_t)s0.z * 16 + ql];
        uint4 v3 = hs4[(size_t)s0.w * 16 + ql];
        uint4 v4 = hs4[(size_t)s1.x * 16 + ql];
        uint4 v5 = hs4[(size_t)s1.y * 16 + ql];
        uint4 v6 = hs4[(size_t)s1.z * 16 + ql];
        uint4 v7 = hs4[(size_t)s1.w * 16 + ql];
        uint4 v8 = hs4[(size_t)s2.x * 16 + ql];
        uint4 v9 = hs4[(size_t)s2.y * 16 + ql];
        uint4 va = hs4[(size_t)s2.z * 16 + ql];
        uint4 vb = hs4[(size_t)s2.w * 16 + ql];
        uint4 vc = hs4[(size_t)s3.x * 16 + ql];
        uint4 vd = hs4[(size_t)s3.y * 16 + ql];
        uint4 ve = hs4[(size_t)s3.z * 16 + ql];
        uint4 vf = hs4[(size_t)s3.w * 16 + ql];
        ACC8(v0) ACC8(v1) ACC8(v2) ACC8(v3) ACC8(v4) ACC8(v5) ACC8(v6) ACC8(v7)
        ACC8(v8) ACC8(v9) ACC8(va) ACC8(vb) ACC8(vc) ACC8(vd) ACC8(ve) ACC8(vf)
    }
    if (i < pend) {                              // exactly 8 remain
        int4 s0 = *(const int4*)(csr + i);
        int4 s1 = *(const int4*)(csr + i + 4);
        uint4 v0 = hs4[(size_t)s0.x * 16 + ql];
        uint4 v1 = hs4[(size_t)s0.y * 16 + ql];
        uint4 v2 = hs4[(size_t)s0.z * 16 + ql];
        uint4 v3 = hs4[(size_t)s0.w * 16 + ql];
        uint4 v4 = hs4[(size_t)s1.x * 16 + ql];
        uint4 v5 = hs4[(size_t)s1.y * 16 + ql];
        uint4 v6 = hs4[(size_t)s1.z * 16 + ql];
        uint4 v7 = hs4[(size_t)s1.w * 16 + ql];
        ACC8(v0) ACC8(v1) ACC8(v2) ACC8(v3) ACC8(v4) ACC8(v5) ACC8(v6) ACC8(v7)
    }
    float o[8] = {};
    if (active) {
        float dv = dinv[node];
        float4 b0 = ((const float4*)bias)[ql * 2];
        float4 b1 = ((const float4*)bias)[ql * 2 + 1];
        o[0] = fmaxf(fmaf(a[0], dv, b0.x), 0.f);
        o[1] = fmaxf(fmaf(a[1], dv, b0.y), 0.f);
        o[2] = fmaxf(fmaf(a[2], dv, b0.z), 0.f);
        o[3] = fmaxf(fmaf(a[3], dv, b0.w), 0.f);
        o[4] = fmaxf(fmaf(a[4], dv, b1.x), 0.f);
        o[5] = fmaxf(fmaf(a[5], dv, b1.y), 0.f);
        o[6] = fmaxf(fmaf(a[6], dv, b1.z), 0.f);
        o[7] = fmaxf(fmaf(a[7], dv, b1.w), 0.f);
    }
    if constexpr (POOL) {
        pacc[grp][ql * 2]     = make_float4(o[0], o[1], o[2], o[3]);
        pacc[grp][ql * 2 + 1] = make_float4(o[4], o[5], o[6], o[7]);
        if (ql == 0) gid[grp] = active ? batch[node] : -1;
        __syncthreads();
        int t = threadIdx.x;
        if (t < 128) {
            float run = 0.f; int prev = -1;
#pragma unroll
            for (int g2 = 0; g2 < 16; ++g2) {
                int g = gid[g2];
                if (g < 0) continue;
                if (g != prev && prev >= 0) { atomicAdd(&psum[prev * 128 + t], run); run = 0.f; }
                run += ((const float*)pacc[g2])[t];
                prev = g;
            }
            if (prev >= 0) atomicAdd(&psum[prev * 128 + t], run);
        }
    } else {
        if (active) {
            uint4 ov;
            ov.x = ((uint)f2b(o[1]) << 16) | (uint)f2b(o[0]);
            ov.y = ((uint)f2b(o[3]) << 16) | (uint)f2b(o[2]);
            ov.z = ((uint)f2b(o[5]) << 16) | (uint)f2b(o[4]);
            ov.w = ((uint)f2b(o[7]) << 16) | (uint)f2b(o[6]);
            outb[(size_t)node * 16 + ql] = ov;
        }
    }
}

// ================= final divide =================

__global__ void k_div(const float* __restrict__ psum, const int* __restrict__ gstart,
                      float* __restrict__ out, int total) {
    int i = blockIdx.x * blockDim.x + threadIdx.x;
    if (i < total) {
        int g = i >> 7;
        float c = (float)(gstart[g + 1] - gstart[g]);
        out[i] = psum[i] / fmaxf(c, 1.f);
    }
}

// ================= launch =================

extern "C" void kernel_launch(void* const* d_in, const int* in_sizes, int n_in,
                              void* d_out, int out_size, void* d_ws, size_t ws_size,
                              hipStream_t stream) {
    const float* x     = (const float*)d_in[0];
    const int*   ei    = (const int*)d_in[1];
    const int*   batch = (const int*)d_in[2];
    const float* W1    = (const float*)d_in[3];
    const float* b1    = (const float*)d_in[4];
    const float* W2    = (const float*)d_in[5];
    const float* b2    = (const float*)d_in[6];
    float* outp = (float*)d_out;

    const int N = in_sizes[2];
    const int E = in_sizes[1] / 2;
    const int D = in_sizes[0] / N;   // 512
    const int H = in_sizes[4];       // 128
    const int G = out_size / H;      // 64
    const int NB = (N + 1023) >> 10; // <= 128

    char* ws = (char*)d_ws;
    size_t off = 0;
    auto alloc = [&](size_t bytes) -> char* {
        char* p = ws + off;
        off = (off + bytes + 255) & ~(size_t)255;
        return p;
    };
    float*  dinv    = (float*)alloc((size_t)(N + 1) * 4);
    uint*   offs    = (uint*)alloc((size_t)N * 4);
    int*    gstart  = (int*)alloc((size_t)(G + 1) * 4);
    float*  psum    = (float*)alloc((size_t)G * H * 4);
    int*    bcur    = (int*)alloc(128 * 4);
    ushort* wt1b    = (ushort*)alloc((size_t)H * D * 2);
    ushort* wt2b    = (ushort*)alloc((size_t)H * H * 2);
    int*    csr     = (int*)alloc((size_t)NB * CCAP * 4);
    uint*   ebuf    = (uint*)alloc((size_t)NB * ECAP * 4);
    char*   hbase   = alloc(((size_t)N * 2 + 8) * H * 2);
    ushort* hb0     = (ushort*)hbase;                        // N rows + zero row
    ushort* hb1     = (ushort*)(hbase + ((size_t)N + 8) * H * 2);
    (void)ws_size; (void)n_in;

    hipMemsetAsync(bcur, 0, 128 * 4, stream);

    int c1b = (128 * D + 255) / 256;
    int c2b = (128 * H + 255) / 256;
    int bb  = (N + 255) / 256;
    int scb = (E + 2047) / 2048;

    k_setup_scatter<<<c1b + c2b + bb + 1 + scb, 256, 0, stream>>>(
        W1, wt1b, D, W2, wt2b, H, batch, N, G, gstart, psum, dinv,
        (uint*)(hb0 + (size_t)N * H), ei, E, NB, bcur, ebuf, c1b, c2b, bb);

    k_bucket_sort<<<NB, 256, 0, stream>>>(ebuf, bcur, N, NB, offs, dinv, csr);

    int gblocks = (N + 127) / 128;
    int sblocks = (N + 15) / 16;
    // layer 1
    k_gemm<0, 8, true><<<gblocks, 256, 0, stream>>>(x, wt1b, dinv, hb0, N);
    k_spmm<0><<<sblocks, 256, 0, stream>>>(
        (const uint4*)hb0, csr, offs, dinv, b1, (uint4*)hb1, nullptr, nullptr, N);
    // layer 2
    k_gemm<1, 2, true><<<gblocks, 256, 0, stream>>>(hb1, wt2b, dinv, hb0, N);
    k_spmm<1><<<sblocks, 256, 0, stream>>>(
        (const uint4*)hb0, csr, offs, dinv, b2, nullptr, psum, batch, N);
    // finalize mean
    k_div<<<(G * H + 255) / 256, 256, 0, stream>>>(psum, gstart, outp, G * H);
}